// Round 7
// baseline (329.112 us; speedup 1.0000x reference)
//
#include <hip/hip_runtime.h>
#include <hip/hip_bf16.h>
#include <cstdint>
#include <cstddef>

typedef unsigned short u16;
typedef unsigned int u32;
typedef __attribute__((ext_vector_type(8))) short bf16x8;   // 8 bf16 = 4 VGPR
typedef __attribute__((ext_vector_type(4))) float f32x4;    // 16x16 MFMA C/D
typedef __attribute__((ext_vector_type(16))) float f32x16;  // 32x32 MFMA C/D
typedef __attribute__((ext_vector_type(4))) unsigned int u32x4;
typedef __attribute__((ext_vector_type(4))) unsigned short u16x4;

#define MFMA16(A,B,C) __builtin_amdgcn_mfma_f32_16x16x32_bf16(A,B,C,0,0,0)
#define MFMA32(A,B,C) __builtin_amdgcn_mfma_f32_32x32x16_bf16(A,B,C,0,0,0)

__device__ __forceinline__ u16 f2bf(float x) {
  __hip_bfloat16 h = __float2bfloat16(x);
  return __builtin_bit_cast(u16, h);
}

// raw v_exp_f32: single trans-pipe instruction (libm exp2f w/o fast-math takes
// the guarded __ocml path). Inputs here are <= ~11.6 (max-tracked); deep
// negatives flush to 0, which is exactly the softmax tail behavior we want.
__device__ __forceinline__ float fast_exp2(float x) {
  float r;
  asm("v_exp_f32 %0, %1" : "=v"(r) : "v"(x));
  return r;
}

__device__ __forceinline__ void async_copy16(u16* lds, const u16* g) {
  __builtin_amdgcn_global_load_lds(
      (const __attribute__((address_space(1))) void*)g,
      (__attribute__((address_space(3))) void*)lds, 16, 0, 0);
}

// ------------------------------------------- fp32 -> bf16, up to 4 arrays/launch
__global__ void cvt4_kernel(const float* __restrict__ i0, const float* __restrict__ i1,
                            const float* __restrict__ i2, const float* __restrict__ i3,
                            u16* __restrict__ o0, u16* __restrict__ o1,
                            u16* __restrict__ o2, u16* __restrict__ o3, int n4) {
  const float* in; u16* out;
  switch (blockIdx.y) {
    case 0:  in = i0; out = o0; break;
    case 1:  in = i1; out = o1; break;
    case 2:  in = i2; out = o2; break;
    default: in = i3; out = o3; break;
  }
  int i = blockIdx.x * blockDim.x + threadIdx.x;
  int stride = gridDim.x * blockDim.x;
  for (; i < n4; i += stride) {
    float4 v = reinterpret_cast<const float4*>(in)[i];
    u16x4 o;
    o.x = f2bf(v.x); o.y = f2bf(v.y); o.z = f2bf(v.z); o.w = f2bf(v.w);
    reinterpret_cast<u16x4*>(out)[i] = o;
  }
}

// ------------------------------------------------- GEMM NT: C = (A*W^T + bias)*scale
// Grid is (m-tiles, n-tiles): linear wg id % 8 = mtile % 8, so the 8 blocks that
// share an A-panel (same m0, all n0) land on ONE XCD -> A read once from HBM/L3
// instead of 8x through every XCD's L2. (Index relabeling only; validated R1.)
template<bool BF16OUT>
__global__ __launch_bounds__(256, 2)
void gemm_nt_bias(const u16* __restrict__ A, const u16* __restrict__ W,
                  const float* __restrict__ bias, void* __restrict__ Cout,
                  int M, int N, int K, float scale) {
  __shared__ __attribute__((aligned(16))) u16 As[128*32];
  __shared__ __attribute__((aligned(16))) u16 Bs[128*32];
  const int t = threadIdx.x;
  const int lane = t & 63, wid = t >> 6;
  const int wr = wid >> 1, wc = wid & 1;
  const int g = lane >> 4, qc = lane & 15;
  const size_t m0 = (size_t)blockIdx.x * 128;
  const size_t n0 = (size_t)blockIdx.y * 128;
  f32x4 acc[4][4] = {};

  for (int k0 = 0; k0 < K; k0 += 32) {
    __syncthreads();
    #pragma unroll
    for (int c = 0; c < 2; ++c) {
      int s = c*256 + t;
      int row = s >> 2, ch = s & 3;
      int sch = ch ^ ((row >> 1) & 3);
      async_copy16(&As[s*8], &A[(m0 + row)*K + k0 + sch*8]);
    }
    #pragma unroll
    for (int c = 0; c < 2; ++c) {
      int s = c*256 + t;
      int row = s >> 2, ch = s & 3;
      int sch = ch ^ ((row >> 1) & 3);
      async_copy16(&Bs[s*8], &W[(n0 + row)*K + k0 + sch*8]);
    }
    __syncthreads();
    bf16x8 af[4], bfr[4];
    #pragma unroll
    for (int i = 0; i < 4; ++i) {
      int r = wr*64 + i*16 + qc;
      int ch = g ^ ((r >> 1) & 3);
      af[i] = *reinterpret_cast<const bf16x8*>(&As[r*32 + ch*8]);
    }
    #pragma unroll
    for (int j = 0; j < 4; ++j) {
      int r = wc*64 + j*16 + qc;
      int ch = g ^ ((r >> 1) & 3);
      bfr[j] = *reinterpret_cast<const bf16x8*>(&Bs[r*32 + ch*8]);
    }
    #pragma unroll
    for (int i = 0; i < 4; ++i)
      #pragma unroll
      for (int j = 0; j < 4; ++j)
        acc[i][j] = MFMA16(af[i], bfr[j], acc[i][j]);
  }

  #pragma unroll
  for (int j = 0; j < 4; ++j) {
    size_t col = n0 + wc*64 + j*16 + qc;
    float bv = bias[col];
    #pragma unroll
    for (int i = 0; i < 4; ++i) {
      #pragma unroll
      for (int r = 0; r < 4; ++r) {
        size_t row = m0 + wr*64 + i*16 + g*4 + r;
        float v = (acc[i][j][r] + bv) * scale;
        if (BF16OUT) ((u16*)Cout)[row*N + col] = f2bf(v);
        else         ((float*)Cout)[row*N + col] = v;
      }
    }
  }
}

// --------------------------------------------------------------- flash attention v19
// Base = v17 (validated PASS). The max/defer machinery is KEPT BIT-IDENTICAL
// (v17 vs v18 proved it is load-bearing: removing it -> 4.9e-2). Single change:
// the denominator moves from the per-tile f32 sum tree (33 VALU ops/lane/tile +
// cross-half shfl + 16 epilogue shfls) to the MFMA pipe: accL = MFMA32(pa, ones,
// accL) inside the existing deferred-PV loop. P values (exp2 inputs, f2bf pack)
// are bit-identical to v17; only l's f32 summation ORDER changes (~1e-7 rel).
// The defer-branch rescale applies to accL exactly as to accO (same coverage:
// tiles 0..kv-1 at branch time, matching v17's l_run *= alpha placement).
__global__ __launch_bounds__(512, 4)
void flash_attn3(const u16* __restrict__ Qp, const u16* __restrict__ Kp,
                 const u16* __restrict__ Vp, u16* __restrict__ O) {
  __shared__ __attribute__((aligned(16))) u16 Ks[2][64*64];
  __shared__ __attribute__((aligned(16))) u16 Vt[3][64*64];
  const int t = threadIdx.x;
  const int w = t >> 6, lane = t & 63;
  const int l31 = lane & 31, hi = lane >> 5;
  const int bh = blockIdx.x;                    // bh fastest -> id%8 = bh%8 (XCD)
  const size_t rowbase = (size_t)(bh >> 4) * 2048;
  const int hoff = (bh & 15) * 64;
  const int q0 = blockIdx.y * 256 + w * 32;
  const float THR = 11.5415603f;   // 8 * log2(e)

  // Q B-frags (Q pre-scaled by 0.125*log2(e) in projection epilogue)
  bf16x8 bq[4];
  {
    const u16* qp = &Qp[(rowbase + q0 + l31) * 1024 + hoff + hi * 8];
    #pragma unroll
    for (int dd = 0; dd < 4; ++dd) bq[dd] = *reinterpret_cast<const bf16x8*>(qp + dd*16);
  }

  // ones B-frag for the accL row-sum MFMA (all-ones matrix in any layout)
  bf16x8 vone;
  #pragma unroll
  for (int i = 0; i < 8; ++i) vone[i] = (short)0x3F80;   // bf16 1.0

  f32x16 accO[2] = {};
  f32x16 accL = {};                 // row-sums of packed P, same C layout as accO
  float m_run = 0.f;                // log2 domain; scores tracked relative to m_run
  u32 pwp[2][8];                    // packed P(t-1)

  const int kvr_s = t >> 3, c_s = t & 7;
  const int sc_s = c_s ^ ((kvr_s >> 3) & 7);      // pre-swizzled K source chunk
  const int vd0_s = (t & 7) * 8;
  const int vcs = kvr_s >> 3;

  // prologue: tile 0
  async_copy16(&Ks[0][t*8], &Kp[(rowbase + kvr_s)*1024 + hoff + sc_s*8]);
  bf16x8 vreg = *reinterpret_cast<const bf16x8*>(&Vp[(rowbase + kvr_s)*1024 + hoff + vd0_s]);

  int wi = 0, ri = 2;   // V write = kv%3, V read (tile kv-1) = (kv+2)%3
  for (int kv = 0; kv < 32; ++kv) {
    const int kb = kv & 1;
    u16* vw = &Vt[0][0] + wi*4096;
    const u16* vrd = &Vt[0][0] + ri*4096;

    // V(kv) regs -> LDS, transposed + chunk-swizzled
    #pragma unroll
    for (int j = 0; j < 8; ++j) {
      int d = vd0_s + j;
      vw[d*64 + ((vcs ^ ((d>>3)&7))*8) + (kvr_s & 7)] = (u16)vreg[j];
    }
    __syncthreads();
    if (kv < 31) {
      const size_t nb = rowbase + (size_t)(kv+1)*64;
      async_copy16(&Ks[kb^1][t*8], &Kp[(nb + kvr_s)*1024 + hoff + sc_s*8]);
      vreg = *reinterpret_cast<const bf16x8*>(&Vp[(nb + kvr_s)*1024 + hoff + vd0_s]);
    }

    // ---- QK^T(kv), swapped; C initialized to -m_run so sacc = S - m_old
    f32x16 sacc[2];
    {
      const float negm = -m_run;
      #pragma unroll
      for (int i = 0; i < 16; ++i) { sacc[0][i] = negm; sacc[1][i] = negm; }
    }
    #pragma unroll
    for (int n = 0; n < 2; ++n) {
      int kvr = n*32 + l31;
      int swz = (kvr >> 3) & 7;
      #pragma unroll
      for (int dd = 0; dd < 4; ++dd) {
        int ch = (2*dd + hi) ^ swz;
        bf16x8 ak = *reinterpret_cast<const bf16x8*>(&Ks[kb][kvr*64 + ch*8]);
        sacc[n] = MFMA32(ak, bq[dd], sacc[n]);
      }
    }

    // ---- deferred PV(kv-1): overlaps softmax VALU below (independent regs)
    if (kv > 0) {
      #pragma unroll
      for (int ks = 0; ks < 4; ++ks) {
        const int n = ks >> 1, kp = ks & 1;
        u32 wA0 = pwp[n][4*kp+0], wA1 = pwp[n][4*kp+1];
        u32 wB0 = pwp[n][4*kp+2], wB1 = pwp[n][4*kp+3];
        u32 s0 = hi ? wA0 : wB0, s1 = hi ? wA1 : wB1;
        u32 r0 = (u32)__shfl_xor((int)s0, 32);
        u32 r1 = (u32)__shfl_xor((int)s1, 32);
        u32 k0 = hi ? wB0 : wA0, k1 = hi ? wB1 : wA1;
        u32x4 fu;
        fu.x = hi ? r0 : k0; fu.y = hi ? r1 : k1;
        fu.z = hi ? k0 : r0; fu.w = hi ? k1 : r1;
        bf16x8 pa = __builtin_bit_cast(bf16x8, fu);
        accL = MFMA32(pa, vone, accL);        // denominator on the matrix pipe
        #pragma unroll
        for (int dt = 0; dt < 2; ++dt) {
          int d = dt*32 + l31;
          int ch = (2*ks + hi) ^ ((d>>3)&7);
          bf16x8 bv = *reinterpret_cast<const bf16x8*>(&vrd[d*64 + ch*8]);
          accO[dt] = MFMA32(pa, bv, accO[dt]);
        }
      }
    }

    // ---- softmax(kv): 3-ary max nest (v_max3-fusable)
    float a0 = fmaxf(fmaxf(sacc[0][0],sacc[0][1]),sacc[0][2]);
    float a1 = fmaxf(fmaxf(sacc[0][3],sacc[0][4]),sacc[0][5]);
    float a2 = fmaxf(fmaxf(sacc[0][6],sacc[0][7]),sacc[0][8]);
    float a3 = fmaxf(fmaxf(sacc[0][9],sacc[0][10]),sacc[0][11]);
    float a4 = fmaxf(fmaxf(sacc[0][12],sacc[0][13]),sacc[0][14]);
    float a5 = fmaxf(fmaxf(sacc[0][15],sacc[1][0]),sacc[1][1]);
    float a6 = fmaxf(fmaxf(sacc[1][2],sacc[1][3]),sacc[1][4]);
    float a7 = fmaxf(fmaxf(sacc[1][5],sacc[1][6]),sacc[1][7]);
    float a8 = fmaxf(fmaxf(sacc[1][8],sacc[1][9]),sacc[1][10]);
    float a9 = fmaxf(fmaxf(sacc[1][11],sacc[1][12]),sacc[1][13]);
    float aA = fmaxf(sacc[1][14],sacc[1][15]);
    float b0 = fmaxf(fmaxf(a0,a1),a2);
    float b1 = fmaxf(fmaxf(a3,a4),a5);
    float b2 = fmaxf(fmaxf(a6,a7),a8);
    float b3 = fmaxf(a9,aA);
    float mloc = fmaxf(fmaxf(b0,b1),fmaxf(b2,b3));
    float mx = fmaxf(mloc, __shfl_xor(mloc, 32));   // relative to m_run

    if (__any(mx > THR)) {   // rare: max grew beyond the defer threshold
      float dm = fmaxf(mx, 0.f);
      float alpha = fast_exp2(-dm);
      m_run += dm;
      #pragma unroll
      for (int n = 0; n < 2; ++n)
        #pragma unroll
        for (int r = 0; r < 16; ++r) sacc[n][r] -= dm;
      #pragma unroll
      for (int r = 0; r < 16; ++r) {
        int qrow = (r&3) + 8*(r>>2) + 4*hi;
        float ar = __shfl(alpha, qrow);
        accO[0][r] *= ar; accO[1][r] *= ar; accL[r] *= ar;
      }
    }

    // ---- exp2 in place (raw v_exp_f32) + RNE f2bf pack (bit-identical to v17)
    #pragma unroll
    for (int n = 0; n < 2; ++n)
      #pragma unroll
      for (int r = 0; r < 16; ++r) sacc[n][r] = fast_exp2(sacc[n][r]);
    #pragma unroll
    for (int n = 0; n < 2; ++n)
      #pragma unroll
      for (int i = 0; i < 8; ++i)
        pwp[n][i] = (u32)f2bf(sacc[n][2*i]) | ((u32)f2bf(sacc[n][2*i+1]) << 16);

    wi = (wi == 2) ? 0 : wi + 1;
    ri = (ri == 2) ? 0 : ri + 1;
  }

  // ---- epilogue PV(31)
  {
    const u16* vrd = &Vt[0][0] + ri*4096;
    #pragma unroll
    for (int ks = 0; ks < 4; ++ks) {
      const int n = ks >> 1, kp = ks & 1;
      u32 wA0 = pwp[n][4*kp+0], wA1 = pwp[n][4*kp+1];
      u32 wB0 = pwp[n][4*kp+2], wB1 = pwp[n][4*kp+3];
      u32 s0 = hi ? wA0 : wB0, s1 = hi ? wA1 : wB1;
      u32 r0 = (u32)__shfl_xor((int)s0, 32);
      u32 r1 = (u32)__shfl_xor((int)s1, 32);
      u32 k0 = hi ? wB0 : wA0, k1 = hi ? wB1 : wA1;
      u32x4 fu;
      fu.x = hi ? r0 : k0; fu.y = hi ? r1 : k1;
      fu.z = hi ? k0 : r0; fu.w = hi ? k1 : r1;
      bf16x8 pa = __builtin_bit_cast(bf16x8, fu);
      accL = MFMA32(pa, vone, accL);
      #pragma unroll
      for (int dt = 0; dt < 2; ++dt) {
        int d = dt*32 + l31;
        int ch = (2*ks + hi) ^ ((d>>3)&7);
        bf16x8 bv = *reinterpret_cast<const bf16x8*>(&vrd[d*64 + ch*8]);
        accO[dt] = MFMA32(pa, bv, accO[dt]);
      }
    }
  }

  // ---- epilogue: accL[r] is the denominator for the SAME q-row as accO[*][r]
  // (identical C layout; B=ones makes it column-independent) -> element-wise.
  #pragma unroll
  for (int r = 0; r < 16; ++r) {
    int qrow = (r&3) + 8*(r>>2) + 4*hi;
    float lv = 1.0f / accL[r];
    size_t orow = rowbase + q0 + qrow;
    O[orow*1024 + hoff + l31]      = f2bf(accO[0][r] * lv);
    O[orow*1024 + hoff + 32 + l31] = f2bf(accO[1][r] * lv);
  }
}

// ------------------------------------------------------------------------------
extern "C" void kernel_launch(void* const* d_in, const int* in_sizes, int n_in,
                              void* d_out, int out_size, void* d_ws, size_t ws_size,
                              hipStream_t stream) {
  (void)in_sizes; (void)n_in; (void)out_size; (void)ws_size;
  const float* query = (const float*)d_in[0];
  const float* key   = (const float*)d_in[1];
  const float* value = (const float*)d_in[2];
  const float* W_q   = (const float*)d_in[3];
  const float* b_q   = (const float*)d_in[4];
  const float* W_k   = (const float*)d_in[5];
  const float* b_k   = (const float*)d_in[6];
  const float* W_v   = (const float*)d_in[7];
  const float* b_v   = (const float*)d_in[8];
  const float* W_o   = (const float*)d_in[9];
  const float* b_o   = (const float*)d_in[10];

  const size_t sz_t = (size_t)8192 * 1024;
  const size_t sz_w = (size_t)1024 * 1024;
  u16* ws = (u16*)d_ws;
  u16* xq = ws;                 // also attn-output staging after Q-GEMM consumes it
  u16* xk = ws + 1*sz_t;
  u16* xv = ws + 2*sz_t;
  u16* Qp = ws + 3*sz_t;
  u16* Kp = ws + 4*sz_t;
  u16* Vp = ws + 5*sz_t;
  u16* wq = ws + 6*sz_t;
  u16* wk = wq + sz_w;
  u16* wv = wq + 2*sz_w;
  u16* wo = wq + 3*sz_w;

  const float SCL = 0.125f * 1.44269504089f;  // softmax scale, folded into Q proj

  cvt4_kernel<<<dim3(512, 4), 256, 0, stream>>>(W_q, W_k, W_v, W_o,
                                                wq, wk, wv, wo, (int)(sz_w/4));
  cvt4_kernel<<<dim3(2048, 3), 256, 0, stream>>>(query, key, value, value,
                                                 xq, xk, xv, xv, (int)(sz_t/4));

  // grid = (m-tiles, n-tiles): A-panel sharers co-locate per XCD
  dim3 gg(8192/128, 1024/128);
  gemm_nt_bias<true><<<gg, 256, 0, stream>>>(xq, wq, b_q, Qp, 8192, 1024, 1024, SCL);
  gemm_nt_bias<true><<<gg, 256, 0, stream>>>(xk, wk, b_k, Kp, 8192, 1024, 1024, 1.0f);
  gemm_nt_bias<true><<<gg, 256, 0, stream>>>(xv, wv, b_v, Vp, 8192, 1024, 1024, 1.0f);

  // grid = (bh, q-tiles): K/V-panel sharers co-locate per XCD
  flash_attn3<<<dim3(64, 8), 512, 0, stream>>>(Qp, Kp, Vp, xq);

  gemm_nt_bias<false><<<gg, 256, 0, stream>>>(xq, wo, b_o, d_out, 8192, 1024, 1024, 1.0f);
}

// Round 8
// 244.480 us; speedup vs baseline: 1.3462x; 1.3462x over previous
//
#include <hip/hip_runtime.h>
#include <hip/hip_bf16.h>
#include <cstdint>
#include <cstddef>

typedef unsigned short u16;
typedef unsigned int u32;
typedef __attribute__((ext_vector_type(8))) short bf16x8;   // 8 bf16 = 4 VGPR
typedef __attribute__((ext_vector_type(4))) float f32x4;    // 16x16 MFMA C/D
typedef __attribute__((ext_vector_type(16))) float f32x16;  // 32x32 MFMA C/D
typedef __attribute__((ext_vector_type(4))) unsigned int u32x4;
typedef __attribute__((ext_vector_type(4))) unsigned short u16x4;

#define MFMA16(A,B,C) __builtin_amdgcn_mfma_f32_16x16x32_bf16(A,B,C,0,0,0)
#define MFMA32(A,B,C) __builtin_amdgcn_mfma_f32_32x32x16_bf16(A,B,C,0,0,0)

__device__ __forceinline__ u16 f2bf(float x) {
  __hip_bfloat16 h = __float2bfloat16(x);
  return __builtin_bit_cast(u16, h);
}

// raw v_exp_f32: single trans-pipe instruction (libm exp2f w/o fast-math takes
// the guarded __ocml path). Inputs here are <= ~11.6 (max-tracked); deep
// negatives flush to 0, which is exactly the softmax tail behavior we want.
__device__ __forceinline__ float fast_exp2(float x) {
  float r;
  asm("v_exp_f32 %0, %1" : "=v"(r) : "v"(x));
  return r;
}

__device__ __forceinline__ void async_copy16(u16* lds, const u16* g) {
  __builtin_amdgcn_global_load_lds(
      (const __attribute__((address_space(1))) void*)g,
      (__attribute__((address_space(3))) void*)lds, 16, 0, 0);
}

// ------------------------------------------- fp32 -> bf16, up to 4 arrays/launch
__global__ void cvt4_kernel(const float* __restrict__ i0, const float* __restrict__ i1,
                            const float* __restrict__ i2, const float* __restrict__ i3,
                            u16* __restrict__ o0, u16* __restrict__ o1,
                            u16* __restrict__ o2, u16* __restrict__ o3, int n4) {
  const float* in; u16* out;
  switch (blockIdx.y) {
    case 0:  in = i0; out = o0; break;
    case 1:  in = i1; out = o1; break;
    case 2:  in = i2; out = o2; break;
    default: in = i3; out = o3; break;
  }
  int i = blockIdx.x * blockDim.x + threadIdx.x;
  int stride = gridDim.x * blockDim.x;
  for (; i < n4; i += stride) {
    float4 v = reinterpret_cast<const float4*>(in)[i];
    u16x4 o;
    o.x = f2bf(v.x); o.y = f2bf(v.y); o.z = f2bf(v.z); o.w = f2bf(v.w);
    reinterpret_cast<u16x4*>(out)[i] = o;
  }
}

// ------------------------------------------------- GEMM NT: C = (A*W^T + bias)*scale
// v2: T3-minimum 2-phase pipeline (double-buffered LDS). Per K-step: ONE barrier
// (whose implicit vmcnt(0) drains the prefetch issued LAST step, exactly when the
// data is needed), then issue next tile's global_load_lds, then compute current
// tile while those loads fly. Replaces the old stage->barrier->compute->barrier
// structure where every wave idled through the full HBM latency each step.
// Math / fragment layout / MFMA order unchanged -> bit-identical output.
// Grid is (m-tiles, n-tiles): A-panel sharers co-locate per XCD (validated R1).
template<bool BF16OUT>
__global__ __launch_bounds__(256, 2)
void gemm_nt_bias(const u16* __restrict__ A, const u16* __restrict__ W,
                  const float* __restrict__ bias, void* __restrict__ Cout,
                  int M, int N, int K, float scale) {
  __shared__ __attribute__((aligned(16))) u16 As[2][128*32];
  __shared__ __attribute__((aligned(16))) u16 Bs[2][128*32];
  const int t = threadIdx.x;
  const int lane = t & 63, wid = t >> 6;
  const int wr = wid >> 1, wc = wid & 1;
  const int g = lane >> 4, qc = lane & 15;
  const size_t m0 = (size_t)blockIdx.x * 128;
  const size_t n0 = (size_t)blockIdx.y * 128;
  f32x4 acc[4][4] = {};

#define GSTAGE(buf, k0_) do {                                         \
    _Pragma("unroll")                                                 \
    for (int c = 0; c < 2; ++c) {                                     \
      int s = c*256 + t;                                              \
      int row = s >> 2, ch = s & 3;                                   \
      int sch = ch ^ ((row >> 1) & 3);                                \
      async_copy16(&As[buf][s*8], &A[(m0 + row)*K + (k0_) + sch*8]);  \
    }                                                                 \
    _Pragma("unroll")                                                 \
    for (int c = 0; c < 2; ++c) {                                     \
      int s = c*256 + t;                                              \
      int row = s >> 2, ch = s & 3;                                   \
      int sch = ch ^ ((row >> 1) & 3);                                \
      async_copy16(&Bs[buf][s*8], &W[(n0 + row)*K + (k0_) + sch*8]);  \
    }                                                                 \
  } while (0)

  GSTAGE(0, 0);                 // prologue prefetch, in flight until first barrier
  int cur = 0;
  for (int k0 = 0; k0 < K; k0 += 32) {
    __syncthreads();            // implicit vmcnt(0): buf[cur] ready; prev reads done
    if (k0 + 32 < K) GSTAGE(cur ^ 1, k0 + 32);   // prefetch overlaps MFMA below
    bf16x8 af[4], bfr[4];
    #pragma unroll
    for (int i = 0; i < 4; ++i) {
      int r = wr*64 + i*16 + qc;
      int ch = g ^ ((r >> 1) & 3);
      af[i] = *reinterpret_cast<const bf16x8*>(&As[cur][r*32 + ch*8]);
    }
    #pragma unroll
    for (int j = 0; j < 4; ++j) {
      int r = wc*64 + j*16 + qc;
      int ch = g ^ ((r >> 1) & 3);
      bfr[j] = *reinterpret_cast<const bf16x8*>(&Bs[cur][r*32 + ch*8]);
    }
    #pragma unroll
    for (int i = 0; i < 4; ++i)
      #pragma unroll
      for (int j = 0; j < 4; ++j)
        acc[i][j] = MFMA16(af[i], bfr[j], acc[i][j]);
    cur ^= 1;
  }
#undef GSTAGE

  #pragma unroll
  for (int j = 0; j < 4; ++j) {
    size_t col = n0 + wc*64 + j*16 + qc;
    float bv = bias[col];
    #pragma unroll
    for (int i = 0; i < 4; ++i) {
      #pragma unroll
      for (int r = 0; r < 4; ++r) {
        size_t row = m0 + wr*64 + i*16 + g*4 + r;
        float v = (acc[i][j][r] + bv) * scale;
        if (BF16OUT) ((u16*)Cout)[row*N + col] = f2bf(v);
        else         ((float*)Cout)[row*N + col] = v;
      }
    }
  }
}

// --------------------------------------------------------------- flash attention v17
// FROZEN at v17 (validated PASS, 113.5 us). Session evidence: max/defer machinery
// is load-bearing (v18: removal -> 4.9e-2); asm permlane32_swap is hazard-unsafe
// (v16: NaN); accL denominator-on-MFMA spills registers at launch_bounds(512,4)
// (v19: +330 MB scratch traffic, 200 us). Do not touch without new evidence.
__global__ __launch_bounds__(512, 4)
void flash_attn3(const u16* __restrict__ Qp, const u16* __restrict__ Kp,
                 const u16* __restrict__ Vp, u16* __restrict__ O) {
  __shared__ __attribute__((aligned(16))) u16 Ks[2][64*64];
  __shared__ __attribute__((aligned(16))) u16 Vt[3][64*64];
  const int t = threadIdx.x;
  const int w = t >> 6, lane = t & 63;
  const int l31 = lane & 31, hi = lane >> 5;
  const int bh = blockIdx.x;                    // bh fastest -> id%8 = bh%8 (XCD)
  const size_t rowbase = (size_t)(bh >> 4) * 2048;
  const int hoff = (bh & 15) * 64;
  const int q0 = blockIdx.y * 256 + w * 32;
  const float THR = 11.5415603f;   // 8 * log2(e)

  // Q B-frags (Q pre-scaled by 0.125*log2(e) in projection epilogue)
  bf16x8 bq[4];
  {
    const u16* qp = &Qp[(rowbase + q0 + l31) * 1024 + hoff + hi * 8];
    #pragma unroll
    for (int dd = 0; dd < 4; ++dd) bq[dd] = *reinterpret_cast<const bf16x8*>(qp + dd*16);
  }

  f32x16 accO[2] = {};
  float m_run = 0.f, l_run = 0.f;   // log2 domain; scores tracked relative to m_run
  u32 pwp[2][8];                    // packed P(t-1)

  const int kvr_s = t >> 3, c_s = t & 7;
  const int sc_s = c_s ^ ((kvr_s >> 3) & 7);      // pre-swizzled K source chunk
  const int vd0_s = (t & 7) * 8;
  const int vcs = kvr_s >> 3;

  // prologue: tile 0
  async_copy16(&Ks[0][t*8], &Kp[(rowbase + kvr_s)*1024 + hoff + sc_s*8]);
  bf16x8 vreg = *reinterpret_cast<const bf16x8*>(&Vp[(rowbase + kvr_s)*1024 + hoff + vd0_s]);

  int wi = 0, ri = 2;   // V write = kv%3, V read (tile kv-1) = (kv+2)%3
  for (int kv = 0; kv < 32; ++kv) {
    const int kb = kv & 1;
    u16* vw = &Vt[0][0] + wi*4096;
    const u16* vrd = &Vt[0][0] + ri*4096;

    // V(kv) regs -> LDS, transposed + chunk-swizzled
    #pragma unroll
    for (int j = 0; j < 8; ++j) {
      int d = vd0_s + j;
      vw[d*64 + ((vcs ^ ((d>>3)&7))*8) + (kvr_s & 7)] = (u16)vreg[j];
    }
    __syncthreads();
    if (kv < 31) {
      const size_t nb = rowbase + (size_t)(kv+1)*64;
      async_copy16(&Ks[kb^1][t*8], &Kp[(nb + kvr_s)*1024 + hoff + sc_s*8]);
      vreg = *reinterpret_cast<const bf16x8*>(&Vp[(nb + kvr_s)*1024 + hoff + vd0_s]);
    }

    // ---- QK^T(kv), swapped; C initialized to -m_run so sacc = S - m_old
    f32x16 sacc[2];
    {
      const float negm = -m_run;
      #pragma unroll
      for (int i = 0; i < 16; ++i) { sacc[0][i] = negm; sacc[1][i] = negm; }
    }
    #pragma unroll
    for (int n = 0; n < 2; ++n) {
      int kvr = n*32 + l31;
      int swz = (kvr >> 3) & 7;
      #pragma unroll
      for (int dd = 0; dd < 4; ++dd) {
        int ch = (2*dd + hi) ^ swz;
        bf16x8 ak = *reinterpret_cast<const bf16x8*>(&Ks[kb][kvr*64 + ch*8]);
        sacc[n] = MFMA32(ak, bq[dd], sacc[n]);
      }
    }

    // ---- deferred PV(kv-1): overlaps softmax VALU below (independent regs)
    if (kv > 0) {
      #pragma unroll
      for (int ks = 0; ks < 4; ++ks) {
        const int n = ks >> 1, kp = ks & 1;
        u32 wA0 = pwp[n][4*kp+0], wA1 = pwp[n][4*kp+1];
        u32 wB0 = pwp[n][4*kp+2], wB1 = pwp[n][4*kp+3];
        u32 s0 = hi ? wA0 : wB0, s1 = hi ? wA1 : wB1;
        u32 r0 = (u32)__shfl_xor((int)s0, 32);
        u32 r1 = (u32)__shfl_xor((int)s1, 32);
        u32 k0 = hi ? wB0 : wA0, k1 = hi ? wB1 : wA1;
        u32x4 fu;
        fu.x = hi ? r0 : k0; fu.y = hi ? r1 : k1;
        fu.z = hi ? k0 : r0; fu.w = hi ? k1 : r1;
        bf16x8 pa = __builtin_bit_cast(bf16x8, fu);
        #pragma unroll
        for (int dt = 0; dt < 2; ++dt) {
          int d = dt*32 + l31;
          int ch = (2*ks + hi) ^ ((d>>3)&7);
          bf16x8 bv = *reinterpret_cast<const bf16x8*>(&vrd[d*64 + ch*8]);
          accO[dt] = MFMA32(pa, bv, accO[dt]);
        }
      }
    }

    // ---- softmax(kv): 3-ary max nest (v_max3-fusable)
    float a0 = fmaxf(fmaxf(sacc[0][0],sacc[0][1]),sacc[0][2]);
    float a1 = fmaxf(fmaxf(sacc[0][3],sacc[0][4]),sacc[0][5]);
    float a2 = fmaxf(fmaxf(sacc[0][6],sacc[0][7]),sacc[0][8]);
    float a3 = fmaxf(fmaxf(sacc[0][9],sacc[0][10]),sacc[0][11]);
    float a4 = fmaxf(fmaxf(sacc[0][12],sacc[0][13]),sacc[0][14]);
    float a5 = fmaxf(fmaxf(sacc[0][15],sacc[1][0]),sacc[1][1]);
    float a6 = fmaxf(fmaxf(sacc[1][2],sacc[1][3]),sacc[1][4]);
    float a7 = fmaxf(fmaxf(sacc[1][5],sacc[1][6]),sacc[1][7]);
    float a8 = fmaxf(fmaxf(sacc[1][8],sacc[1][9]),sacc[1][10]);
    float a9 = fmaxf(fmaxf(sacc[1][11],sacc[1][12]),sacc[1][13]);
    float aA = fmaxf(sacc[1][14],sacc[1][15]);
    float b0 = fmaxf(fmaxf(a0,a1),a2);
    float b1 = fmaxf(fmaxf(a3,a4),a5);
    float b2 = fmaxf(fmaxf(a6,a7),a8);
    float b3 = fmaxf(a9,aA);
    float mloc = fmaxf(fmaxf(b0,b1),fmaxf(b2,b3));
    float mx = fmaxf(mloc, __shfl_xor(mloc, 32));   // relative to m_run

    if (__any(mx > THR)) {   // rare: max grew beyond the defer threshold
      float dm = fmaxf(mx, 0.f);
      float alpha = fast_exp2(-dm);
      m_run += dm;
      l_run *= alpha;
      #pragma unroll
      for (int n = 0; n < 2; ++n)
        #pragma unroll
        for (int r = 0; r < 16; ++r) sacc[n][r] -= dm;
      #pragma unroll
      for (int r = 0; r < 16; ++r) {
        int qrow = (r&3) + 8*(r>>2) + 4*hi;
        float ar = __shfl(alpha, qrow);
        accO[0][r] *= ar; accO[1][r] *= ar;
      }
    }

    // ---- exp2 in place (raw v_exp_f32), RNE f2bf pack, sum tree
    #pragma unroll
    for (int n = 0; n < 2; ++n)
      #pragma unroll
      for (int r = 0; r < 16; ++r) sacc[n][r] = fast_exp2(sacc[n][r]);
    #pragma unroll
    for (int n = 0; n < 2; ++n)
      #pragma unroll
      for (int i = 0; i < 8; ++i)
        pwp[n][i] = (u32)f2bf(sacc[n][2*i]) | ((u32)f2bf(sacc[n][2*i+1]) << 16);
    float ts[16];
    #pragma unroll
    for (int i = 0; i < 16; ++i) ts[i] = sacc[0][i] + sacc[1][i];
    #pragma unroll
    for (int off = 8; off >= 1; off >>= 1)
      #pragma unroll
      for (int i = 0; i < off; ++i) ts[i] += ts[i + off];
    l_run += ts[0] + __shfl_xor(ts[0], 32);

    wi = (wi == 2) ? 0 : wi + 1;
    ri = (ri == 2) ? 0 : ri + 1;
  }

  // ---- epilogue PV(31)
  {
    const u16* vrd = &Vt[0][0] + ri*4096;
    #pragma unroll
    for (int ks = 0; ks < 4; ++ks) {
      const int n = ks >> 1, kp = ks & 1;
      u32 wA0 = pwp[n][4*kp+0], wA1 = pwp[n][4*kp+1];
      u32 wB0 = pwp[n][4*kp+2], wB1 = pwp[n][4*kp+3];
      u32 s0 = hi ? wA0 : wB0, s1 = hi ? wA1 : wB1;
      u32 r0 = (u32)__shfl_xor((int)s0, 32);
      u32 r1 = (u32)__shfl_xor((int)s1, 32);
      u32 k0 = hi ? wB0 : wA0, k1 = hi ? wB1 : wA1;
      u32x4 fu;
      fu.x = hi ? r0 : k0; fu.y = hi ? r1 : k1;
      fu.z = hi ? k0 : r0; fu.w = hi ? k1 : r1;
      bf16x8 pa = __builtin_bit_cast(bf16x8, fu);
      #pragma unroll
      for (int dt = 0; dt < 2; ++dt) {
        int d = dt*32 + l31;
        int ch = (2*ks + hi) ^ ((d>>3)&7);
        bf16x8 bv = *reinterpret_cast<const bf16x8*>(&vrd[d*64 + ch*8]);
        accO[dt] = MFMA32(pa, bv, accO[dt]);
      }
    }
  }

  // ---- epilogue: O[q'][d] * (1/l[q']), l for row q' pulled from lane q'
  float linv = 1.0f / l_run;
  #pragma unroll
  for (int r = 0; r < 16; ++r) {
    int qrow = (r&3) + 8*(r>>2) + 4*hi;
    float lv = __shfl(linv, qrow);
    size_t orow = rowbase + q0 + qrow;
    O[orow*1024 + hoff + l31]      = f2bf(accO[0][r] * lv);
    O[orow*1024 + hoff + 32 + l31] = f2bf(accO[1][r] * lv);
  }
}

// ------------------------------------------------------------------------------
extern "C" void kernel_launch(void* const* d_in, const int* in_sizes, int n_in,
                              void* d_out, int out_size, void* d_ws, size_t ws_size,
                              hipStream_t stream) {
  (void)in_sizes; (void)n_in; (void)out_size; (void)ws_size;
  const float* query = (const float*)d_in[0];
  const float* key   = (const float*)d_in[1];
  const float* value = (const float*)d_in[2];
  const float* W_q   = (const float*)d_in[3];
  const float* b_q   = (const float*)d_in[4];
  const float* W_k   = (const float*)d_in[5];
  const float* b_k   = (const float*)d_in[6];
  const float* W_v   = (const float*)d_in[7];
  const float* b_v   = (const float*)d_in[8];
  const float* W_o   = (const float*)d_in[9];
  const float* b_o   = (const float*)d_in[10];

  const size_t sz_t = (size_t)8192 * 1024;
  const size_t sz_w = (size_t)1024 * 1024;
  u16* ws = (u16*)d_ws;
  u16* xq = ws;                 // also attn-output staging after Q-GEMM consumes it
  u16* xk = ws + 1*sz_t;
  u16* xv = ws + 2*sz_t;
  u16* Qp = ws + 3*sz_t;
  u16* Kp = ws + 4*sz_t;
  u16* Vp = ws + 5*sz_t;
  u16* wq = ws + 6*sz_t;
  u16* wk = wq + sz_w;
  u16* wv = wq + 2*sz_w;
  u16* wo = wq + 3*sz_w;

  const float SCL = 0.125f * 1.44269504089f;  // softmax scale, folded into Q proj

  cvt4_kernel<<<dim3(512, 4), 256, 0, stream>>>(W_q, W_k, W_v, W_o,
                                                wq, wk, wv, wo, (int)(sz_w/4));
  cvt4_kernel<<<dim3(2048, 3), 256, 0, stream>>>(query, key, value, value,
                                                 xq, xk, xv, xv, (int)(sz_t/4));

  // grid = (m-tiles, n-tiles): A-panel sharers co-locate per XCD
  dim3 gg(8192/128, 1024/128);
  gemm_nt_bias<true><<<gg, 256, 0, stream>>>(xq, wq, b_q, Qp, 8192, 1024, 1024, SCL);
  gemm_nt_bias<true><<<gg, 256, 0, stream>>>(xk, wk, b_k, Kp, 8192, 1024, 1024, 1.0f);
  gemm_nt_bias<true><<<gg, 256, 0, stream>>>(xv, wv, b_v, Vp, 8192, 1024, 1024, 1.0f);

  // grid = (bh, q-tiles): K/V-panel sharers co-locate per XCD
  flash_attn3<<<dim3(64, 8), 512, 0, stream>>>(Qp, Kp, Vp, xq);

  gemm_nt_bias<false><<<gg, 256, 0, stream>>>(xq, wo, b_o, d_out, 8192, 1024, 1024, 1.0f);
}

// Round 9
// 229.210 us; speedup vs baseline: 1.4359x; 1.0666x over previous
//
#include <hip/hip_runtime.h>
#include <hip/hip_bf16.h>
#include <cstdint>
#include <cstddef>

typedef unsigned short u16;
typedef unsigned int u32;
typedef __attribute__((ext_vector_type(8))) short bf16x8;   // 8 bf16 = 4 VGPR
typedef __attribute__((ext_vector_type(4))) float f32x4;    // 16x16 MFMA C/D
typedef __attribute__((ext_vector_type(16))) float f32x16;  // 32x32 MFMA C/D
typedef __attribute__((ext_vector_type(4))) unsigned int u32x4;
typedef __attribute__((ext_vector_type(4))) unsigned short u16x4;

#define MFMA16(A,B,C) __builtin_amdgcn_mfma_f32_16x16x32_bf16(A,B,C,0,0,0)
#define MFMA32(A,B,C) __builtin_amdgcn_mfma_f32_32x32x16_bf16(A,B,C,0,0,0)

__device__ __forceinline__ u16 f2bf(float x) {
  __hip_bfloat16 h = __float2bfloat16(x);
  return __builtin_bit_cast(u16, h);
}

// raw v_exp_f32: single trans-pipe instruction (libm exp2f w/o fast-math takes
// the guarded __ocml path). Inputs here are <= ~11.6 (max-tracked); deep
// negatives flush to 0, which is exactly the softmax tail behavior we want.
__device__ __forceinline__ float fast_exp2(float x) {
  float r;
  asm("v_exp_f32 %0, %1" : "=v"(r) : "v"(x));
  return r;
}

__device__ __forceinline__ void async_copy16(u16* lds, const u16* g) {
  __builtin_amdgcn_global_load_lds(
      (const __attribute__((address_space(1))) void*)g,
      (__attribute__((address_space(3))) void*)lds, 16, 0, 0);
}

// ------------------------------------------- fp32 -> bf16, up to 4 arrays/launch
__global__ void cvt4_kernel(const float* __restrict__ i0, const float* __restrict__ i1,
                            const float* __restrict__ i2, const float* __restrict__ i3,
                            u16* __restrict__ o0, u16* __restrict__ o1,
                            u16* __restrict__ o2, u16* __restrict__ o3, int n4) {
  const float* in; u16* out;
  switch (blockIdx.y) {
    case 0:  in = i0; out = o0; break;
    case 1:  in = i1; out = o1; break;
    case 2:  in = i2; out = o2; break;
    default: in = i3; out = o3; break;
  }
  int i = blockIdx.x * blockDim.x + threadIdx.x;
  int stride = gridDim.x * blockDim.x;
  for (; i < n4; i += stride) {
    float4 v = reinterpret_cast<const float4*>(in)[i];
    u16x4 o;
    o.x = f2bf(v.x); o.y = f2bf(v.y); o.z = f2bf(v.z); o.w = f2bf(v.w);
    reinterpret_cast<u16x4*>(out)[i] = o;
  }
}

// ------------------------------------------------- GEMM NT: C = (A*W^T + bias)*scale
// v3: 512-thread blocks (8 waves = 2 row-halves x 4 col-quarters, 64x32 output
// each, acc[4][2]) on the same 128x128 tile. R8 showed dbuf alone was neutral at
// 2 waves/SIMD (nothing to overlap with); this doubles resident waves/SIMD (2->4)
// at unchanged per-element MFMA chains -> bit-identical output, better hiding.
// Staging image identical to v1/v2 (one 512-thread pass instead of 2x256).
// Grid (m-tiles, n-tiles[, qkv]): A-panel sharers co-locate per XCD (id%8 = x%8).
template<bool BF16OUT>
__device__ __forceinline__ void gemm_body(const u16* __restrict__ A, const u16* __restrict__ W,
                                          const float* __restrict__ bias, void* __restrict__ Cout,
                                          int N, int K, float scale) {
  __shared__ __attribute__((aligned(16))) u16 As[2][128*32];
  __shared__ __attribute__((aligned(16))) u16 Bs[2][128*32];
  const int t = threadIdx.x;
  const int lane = t & 63, wid = t >> 6;          // wid 0..7
  const int wr = wid >> 2, wc = wid & 3;          // 2 row-halves x 4 col-quarters
  const int g = lane >> 4, qc = lane & 15;
  const size_t m0 = (size_t)blockIdx.x * 128;
  const size_t n0 = (size_t)blockIdx.y * 128;
  f32x4 acc[4][2] = {};

  const int srow = t >> 2;                        // staging: 512 thr x 16B = 8KB tile
  const int ssch = (t & 3) ^ ((srow >> 1) & 3);   // chunk swizzle (as v1/v2)

#define GSTAGE(buf, k0_) do {                                            \
    async_copy16(&As[buf][t*8], &A[(m0 + srow)*K + (k0_) + ssch*8]);     \
    async_copy16(&Bs[buf][t*8], &W[(n0 + srow)*K + (k0_) + ssch*8]);     \
  } while (0)

  GSTAGE(0, 0);                 // prologue prefetch, drained by first barrier
  int cur = 0;
  for (int k0 = 0; k0 < K; k0 += 32) {
    __syncthreads();            // implicit vmcnt(0): buf[cur] ready; prev reads done
    if (k0 + 32 < K) GSTAGE(cur ^ 1, k0 + 32);   // prefetch overlaps MFMA below
    bf16x8 af[4], bfr[2];
    #pragma unroll
    for (int i = 0; i < 4; ++i) {
      int r = wr*64 + i*16 + qc;
      int ch = g ^ ((r >> 1) & 3);
      af[i] = *reinterpret_cast<const bf16x8*>(&As[cur][r*32 + ch*8]);
    }
    #pragma unroll
    for (int j = 0; j < 2; ++j) {
      int r = wc*32 + j*16 + qc;
      int ch = g ^ ((r >> 1) & 3);
      bfr[j] = *reinterpret_cast<const bf16x8*>(&Bs[cur][r*32 + ch*8]);
    }
    #pragma unroll
    for (int i = 0; i < 4; ++i)
      #pragma unroll
      for (int j = 0; j < 2; ++j)
        acc[i][j] = MFMA16(af[i], bfr[j], acc[i][j]);
    cur ^= 1;
  }
#undef GSTAGE

  #pragma unroll
  for (int j = 0; j < 2; ++j) {
    size_t col = n0 + wc*32 + j*16 + qc;
    float bv = bias[col];
    #pragma unroll
    for (int i = 0; i < 4; ++i) {
      #pragma unroll
      for (int r = 0; r < 4; ++r) {
        size_t row = m0 + wr*64 + i*16 + g*4 + r;
        float v = (acc[i][j][r] + bv) * scale;
        if (BF16OUT) ((u16*)Cout)[row*N + col] = f2bf(v);
        else         ((float*)Cout)[row*N + col] = v;
      }
    }
  }
}

// Q/K/V projections fused into one launch via blockIdx.z: removes 2 launch gaps
// and overlaps the three GEMMs' tails. id%8 unchanged (z contributes 512*z).
__global__ __launch_bounds__(512, 2)
void gemm_qkv(const u16* __restrict__ xq, const u16* __restrict__ xk,
              const u16* __restrict__ xv, const u16* __restrict__ wq,
              const u16* __restrict__ wk, const u16* __restrict__ wv,
              const float* __restrict__ b_q, const float* __restrict__ b_k,
              const float* __restrict__ b_v, u16* __restrict__ Qp,
              u16* __restrict__ Kp, u16* __restrict__ Vp, float scaleQ) {
  const u16* A; const u16* W; const float* bias; u16* C; float scale;
  switch (blockIdx.z) {
    case 0:  A = xq; W = wq; bias = b_q; C = Qp; scale = scaleQ; break;
    case 1:  A = xk; W = wk; bias = b_k; C = Kp; scale = 1.0f;   break;
    default: A = xv; W = wv; bias = b_v; C = Vp; scale = 1.0f;   break;
  }
  gemm_body<true>(A, W, bias, C, 1024, 1024, scale);
}

__global__ __launch_bounds__(512, 2)
void gemm_out(const u16* __restrict__ A, const u16* __restrict__ W,
              const float* __restrict__ bias, float* __restrict__ C) {
  gemm_body<false>(A, W, bias, C, 1024, 1024, 1.0f);
}

// --------------------------------------------------------------- flash attention v17
// FROZEN at v17 (validated PASS, 113.5 us). Session evidence: max/defer machinery
// is load-bearing (v18: removal -> 4.9e-2); asm permlane32_swap is hazard-unsafe
// (v16: NaN); accL denominator-on-MFMA spills registers at launch_bounds(512,4)
// (v19: +330 MB scratch traffic, 200 us). Do not touch without new evidence.
__global__ __launch_bounds__(512, 4)
void flash_attn3(const u16* __restrict__ Qp, const u16* __restrict__ Kp,
                 const u16* __restrict__ Vp, u16* __restrict__ O) {
  __shared__ __attribute__((aligned(16))) u16 Ks[2][64*64];
  __shared__ __attribute__((aligned(16))) u16 Vt[3][64*64];
  const int t = threadIdx.x;
  const int w = t >> 6, lane = t & 63;
  const int l31 = lane & 31, hi = lane >> 5;
  const int bh = blockIdx.x;                    // bh fastest -> id%8 = bh%8 (XCD)
  const size_t rowbase = (size_t)(bh >> 4) * 2048;
  const int hoff = (bh & 15) * 64;
  const int q0 = blockIdx.y * 256 + w * 32;
  const float THR = 11.5415603f;   // 8 * log2(e)

  // Q B-frags (Q pre-scaled by 0.125*log2(e) in projection epilogue)
  bf16x8 bq[4];
  {
    const u16* qp = &Qp[(rowbase + q0 + l31) * 1024 + hoff + hi * 8];
    #pragma unroll
    for (int dd = 0; dd < 4; ++dd) bq[dd] = *reinterpret_cast<const bf16x8*>(qp + dd*16);
  }

  f32x16 accO[2] = {};
  float m_run = 0.f, l_run = 0.f;   // log2 domain; scores tracked relative to m_run
  u32 pwp[2][8];                    // packed P(t-1)

  const int kvr_s = t >> 3, c_s = t & 7;
  const int sc_s = c_s ^ ((kvr_s >> 3) & 7);      // pre-swizzled K source chunk
  const int vd0_s = (t & 7) * 8;
  const int vcs = kvr_s >> 3;

  // prologue: tile 0
  async_copy16(&Ks[0][t*8], &Kp[(rowbase + kvr_s)*1024 + hoff + sc_s*8]);
  bf16x8 vreg = *reinterpret_cast<const bf16x8*>(&Vp[(rowbase + kvr_s)*1024 + hoff + vd0_s]);

  int wi = 0, ri = 2;   // V write = kv%3, V read (tile kv-1) = (kv+2)%3
  for (int kv = 0; kv < 32; ++kv) {
    const int kb = kv & 1;
    u16* vw = &Vt[0][0] + wi*4096;
    const u16* vrd = &Vt[0][0] + ri*4096;

    // V(kv) regs -> LDS, transposed + chunk-swizzled
    #pragma unroll
    for (int j = 0; j < 8; ++j) {
      int d = vd0_s + j;
      vw[d*64 + ((vcs ^ ((d>>3)&7))*8) + (kvr_s & 7)] = (u16)vreg[j];
    }
    __syncthreads();
    if (kv < 31) {
      const size_t nb = rowbase + (size_t)(kv+1)*64;
      async_copy16(&Ks[kb^1][t*8], &Kp[(nb + kvr_s)*1024 + hoff + sc_s*8]);
      vreg = *reinterpret_cast<const bf16x8*>(&Vp[(nb + kvr_s)*1024 + hoff + vd0_s]);
    }

    // ---- QK^T(kv), swapped; C initialized to -m_run so sacc = S - m_old
    f32x16 sacc[2];
    {
      const float negm = -m_run;
      #pragma unroll
      for (int i = 0; i < 16; ++i) { sacc[0][i] = negm; sacc[1][i] = negm; }
    }
    #pragma unroll
    for (int n = 0; n < 2; ++n) {
      int kvr = n*32 + l31;
      int swz = (kvr >> 3) & 7;
      #pragma unroll
      for (int dd = 0; dd < 4; ++dd) {
        int ch = (2*dd + hi) ^ swz;
        bf16x8 ak = *reinterpret_cast<const bf16x8*>(&Ks[kb][kvr*64 + ch*8]);
        sacc[n] = MFMA32(ak, bq[dd], sacc[n]);
      }
    }

    // ---- deferred PV(kv-1): overlaps softmax VALU below (independent regs)
    if (kv > 0) {
      #pragma unroll
      for (int ks = 0; ks < 4; ++ks) {
        const int n = ks >> 1, kp = ks & 1;
        u32 wA0 = pwp[n][4*kp+0], wA1 = pwp[n][4*kp+1];
        u32 wB0 = pwp[n][4*kp+2], wB1 = pwp[n][4*kp+3];
        u32 s0 = hi ? wA0 : wB0, s1 = hi ? wA1 : wB1;
        u32 r0 = (u32)__shfl_xor((int)s0, 32);
        u32 r1 = (u32)__shfl_xor((int)s1, 32);
        u32 k0 = hi ? wB0 : wA0, k1 = hi ? wB1 : wA1;
        u32x4 fu;
        fu.x = hi ? r0 : k0; fu.y = hi ? r1 : k1;
        fu.z = hi ? k0 : r0; fu.w = hi ? k1 : r1;
        bf16x8 pa = __builtin_bit_cast(bf16x8, fu);
        #pragma unroll
        for (int dt = 0; dt < 2; ++dt) {
          int d = dt*32 + l31;
          int ch = (2*ks + hi) ^ ((d>>3)&7);
          bf16x8 bv = *reinterpret_cast<const bf16x8*>(&vrd[d*64 + ch*8]);
          accO[dt] = MFMA32(pa, bv, accO[dt]);
        }
      }
    }

    // ---- softmax(kv): 3-ary max nest (v_max3-fusable)
    float a0 = fmaxf(fmaxf(sacc[0][0],sacc[0][1]),sacc[0][2]);
    float a1 = fmaxf(fmaxf(sacc[0][3],sacc[0][4]),sacc[0][5]);
    float a2 = fmaxf(fmaxf(sacc[0][6],sacc[0][7]),sacc[0][8]);
    float a3 = fmaxf(fmaxf(sacc[0][9],sacc[0][10]),sacc[0][11]);
    float a4 = fmaxf(fmaxf(sacc[0][12],sacc[0][13]),sacc[0][14]);
    float a5 = fmaxf(fmaxf(sacc[0][15],sacc[1][0]),sacc[1][1]);
    float a6 = fmaxf(fmaxf(sacc[1][2],sacc[1][3]),sacc[1][4]);
    float a7 = fmaxf(fmaxf(sacc[1][5],sacc[1][6]),sacc[1][7]);
    float a8 = fmaxf(fmaxf(sacc[1][8],sacc[1][9]),sacc[1][10]);
    float a9 = fmaxf(fmaxf(sacc[1][11],sacc[1][12]),sacc[1][13]);
    float aA = fmaxf(sacc[1][14],sacc[1][15]);
    float b0 = fmaxf(fmaxf(a0,a1),a2);
    float b1 = fmaxf(fmaxf(a3,a4),a5);
    float b2 = fmaxf(fmaxf(a6,a7),a8);
    float b3 = fmaxf(a9,aA);
    float mloc = fmaxf(fmaxf(b0,b1),fmaxf(b2,b3));
    float mx = fmaxf(mloc, __shfl_xor(mloc, 32));   // relative to m_run

    if (__any(mx > THR)) {   // rare: max grew beyond the defer threshold
      float dm = fmaxf(mx, 0.f);
      float alpha = fast_exp2(-dm);
      m_run += dm;
      l_run *= alpha;
      #pragma unroll
      for (int n = 0; n < 2; ++n)
        #pragma unroll
        for (int r = 0; r < 16; ++r) sacc[n][r] -= dm;
      #pragma unroll
      for (int r = 0; r < 16; ++r) {
        int qrow = (r&3) + 8*(r>>2) + 4*hi;
        float ar = __shfl(alpha, qrow);
        accO[0][r] *= ar; accO[1][r] *= ar;
      }
    }

    // ---- exp2 in place (raw v_exp_f32), RNE f2bf pack, sum tree
    #pragma unroll
    for (int n = 0; n < 2; ++n)
      #pragma unroll
      for (int r = 0; r < 16; ++r) sacc[n][r] = fast_exp2(sacc[n][r]);
    #pragma unroll
    for (int n = 0; n < 2; ++n)
      #pragma unroll
      for (int i = 0; i < 8; ++i)
        pwp[n][i] = (u32)f2bf(sacc[n][2*i]) | ((u32)f2bf(sacc[n][2*i+1]) << 16);
    float ts[16];
    #pragma unroll
    for (int i = 0; i < 16; ++i) ts[i] = sacc[0][i] + sacc[1][i];
    #pragma unroll
    for (int off = 8; off >= 1; off >>= 1)
      #pragma unroll
      for (int i = 0; i < off; ++i) ts[i] += ts[i + off];
    l_run += ts[0] + __shfl_xor(ts[0], 32);

    wi = (wi == 2) ? 0 : wi + 1;
    ri = (ri == 2) ? 0 : ri + 1;
  }

  // ---- epilogue PV(31)
  {
    const u16* vrd = &Vt[0][0] + ri*4096;
    #pragma unroll
    for (int ks = 0; ks < 4; ++ks) {
      const int n = ks >> 1, kp = ks & 1;
      u32 wA0 = pwp[n][4*kp+0], wA1 = pwp[n][4*kp+1];
      u32 wB0 = pwp[n][4*kp+2], wB1 = pwp[n][4*kp+3];
      u32 s0 = hi ? wA0 : wB0, s1 = hi ? wA1 : wB1;
      u32 r0 = (u32)__shfl_xor((int)s0, 32);
      u32 r1 = (u32)__shfl_xor((int)s1, 32);
      u32 k0 = hi ? wB0 : wA0, k1 = hi ? wB1 : wA1;
      u32x4 fu;
      fu.x = hi ? r0 : k0; fu.y = hi ? r1 : k1;
      fu.z = hi ? k0 : r0; fu.w = hi ? k1 : r1;
      bf16x8 pa = __builtin_bit_cast(bf16x8, fu);
      #pragma unroll
      for (int dt = 0; dt < 2; ++dt) {
        int d = dt*32 + l31;
        int ch = (2*ks + hi) ^ ((d>>3)&7);
        bf16x8 bv = *reinterpret_cast<const bf16x8*>(&vrd[d*64 + ch*8]);
        accO[dt] = MFMA32(pa, bv, accO[dt]);
      }
    }
  }

  // ---- epilogue: O[q'][d] * (1/l[q']), l for row q' pulled from lane q'
  float linv = 1.0f / l_run;
  #pragma unroll
  for (int r = 0; r < 16; ++r) {
    int qrow = (r&3) + 8*(r>>2) + 4*hi;
    float lv = __shfl(linv, qrow);
    size_t orow = rowbase + q0 + qrow;
    O[orow*1024 + hoff + l31]      = f2bf(accO[0][r] * lv);
    O[orow*1024 + hoff + 32 + l31] = f2bf(accO[1][r] * lv);
  }
}

// ------------------------------------------------------------------------------
extern "C" void kernel_launch(void* const* d_in, const int* in_sizes, int n_in,
                              void* d_out, int out_size, void* d_ws, size_t ws_size,
                              hipStream_t stream) {
  (void)in_sizes; (void)n_in; (void)out_size; (void)ws_size;
  const float* query = (const float*)d_in[0];
  const float* key   = (const float*)d_in[1];
  const float* value = (const float*)d_in[2];
  const float* W_q   = (const float*)d_in[3];
  const float* b_q   = (const float*)d_in[4];
  const float* W_k   = (const float*)d_in[5];
  const float* b_k   = (const float*)d_in[6];
  const float* W_v   = (const float*)d_in[7];
  const float* b_v   = (const float*)d_in[8];
  const float* W_o   = (const float*)d_in[9];
  const float* b_o   = (const float*)d_in[10];

  const size_t sz_t = (size_t)8192 * 1024;
  const size_t sz_w = (size_t)1024 * 1024;
  u16* ws = (u16*)d_ws;
  u16* xq = ws;                 // also attn-output staging after Q-GEMM consumes it
  u16* xk = ws + 1*sz_t;
  u16* xv = ws + 2*sz_t;
  u16* Qp = ws + 3*sz_t;
  u16* Kp = ws + 4*sz_t;
  u16* Vp = ws + 5*sz_t;
  u16* wq = ws + 6*sz_t;
  u16* wk = wq + sz_w;
  u16* wv = wq + 2*sz_w;
  u16* wo = wq + 3*sz_w;

  const float SCL = 0.125f * 1.44269504089f;  // softmax scale, folded into Q proj

  cvt4_kernel<<<dim3(512, 4), 256, 0, stream>>>(W_q, W_k, W_v, W_o,
                                                wq, wk, wv, wo, (int)(sz_w/4));
  cvt4_kernel<<<dim3(2048, 3), 256, 0, stream>>>(query, key, value, value,
                                                 xq, xk, xv, xv, (int)(sz_t/4));

  // fused QKV projection: grid (m-tiles, n-tiles, 3), A-panel sharers per XCD
  gemm_qkv<<<dim3(8192/128, 1024/128, 3), 512, 0, stream>>>(
      xq, xk, xv, wq, wk, wv, b_q, b_k, b_v, Qp, Kp, Vp, SCL);

  // grid = (bh, q-tiles): K/V-panel sharers co-locate per XCD
  flash_attn3<<<dim3(64, 8), 512, 0, stream>>>(Qp, Kp, Vp, xq);

  gemm_out<<<dim3(8192/128, 1024/128), 512, 0, stream>>>(xq, wo, b_o, (float*)d_out);
}

// Round 10
// 223.537 us; speedup vs baseline: 1.4723x; 1.0254x over previous
//
#include <hip/hip_runtime.h>
#include <hip/hip_bf16.h>
#include <cstdint>
#include <cstddef>

typedef unsigned short u16;
typedef unsigned int u32;
typedef __attribute__((ext_vector_type(8))) short bf16x8;   // 8 bf16 = 4 VGPR
typedef __attribute__((ext_vector_type(4))) float f32x4;    // 16x16 MFMA C/D
typedef __attribute__((ext_vector_type(16))) float f32x16;  // 32x32 MFMA C/D
typedef __attribute__((ext_vector_type(4))) unsigned int u32x4;
typedef __attribute__((ext_vector_type(4))) unsigned short u16x4;

#define MFMA16(A,B,C) __builtin_amdgcn_mfma_f32_16x16x32_bf16(A,B,C,0,0,0)
#define MFMA32(A,B,C) __builtin_amdgcn_mfma_f32_32x32x16_bf16(A,B,C,0,0,0)

__device__ __forceinline__ u16 f2bf(float x) {
  __hip_bfloat16 h = __float2bfloat16(x);
  return __builtin_bit_cast(u16, h);
}

// raw v_exp_f32: single trans-pipe instruction (libm exp2f w/o fast-math takes
// the guarded __ocml path). Inputs here are <= ~11.6 (max-tracked); deep
// negatives flush to 0, which is exactly the softmax tail behavior we want.
__device__ __forceinline__ float fast_exp2(float x) {
  float r;
  asm("v_exp_f32 %0, %1" : "=v"(r) : "v"(x));
  return r;
}

__device__ __forceinline__ void async_copy16(u16* lds, const u16* g) {
  __builtin_amdgcn_global_load_lds(
      (const __attribute__((address_space(1))) void*)g,
      (__attribute__((address_space(3))) void*)lds, 16, 0, 0);
}

// ------------------------------------------- fp32 -> bf16, up to 4 arrays/launch
__global__ void cvt4_kernel(const float* __restrict__ i0, const float* __restrict__ i1,
                            const float* __restrict__ i2, const float* __restrict__ i3,
                            u16* __restrict__ o0, u16* __restrict__ o1,
                            u16* __restrict__ o2, u16* __restrict__ o3, int n4) {
  const float* in; u16* out;
  switch (blockIdx.y) {
    case 0:  in = i0; out = o0; break;
    case 1:  in = i1; out = o1; break;
    case 2:  in = i2; out = o2; break;
    default: in = i3; out = o3; break;
  }
  int i = blockIdx.x * blockDim.x + threadIdx.x;
  int stride = gridDim.x * blockDim.x;
  for (; i < n4; i += stride) {
    float4 v = reinterpret_cast<const float4*>(in)[i];
    u16x4 o;
    o.x = f2bf(v.x); o.y = f2bf(v.y); o.z = f2bf(v.z); o.w = f2bf(v.w);
    reinterpret_cast<u16x4*>(out)[i] = o;
  }
}

// ------------------------------------------------- GEMM NT: C = (A*W^T + bias)*scale
// v4 = v3 (512-thread, 8-wave 2x4, dbuf, validated R9) + F32A path: A is read as
// fp32 and converted in-staging (reg-load float4 x2 -> f2bf x8 -> ds_write_b128),
// producing the SAME LDS image as the old cvt4+global_load_lds pipeline -> output
// bit-identical while the separate 144MB tensor-cvt pass disappears. A-loads are
// issued right after the barrier (T14 split: in flight across the MFMA phase).
// Grid (m-tiles, n-tiles[, qkv]): A-panel sharers co-locate per XCD (id%8 = x%8).
template<bool BF16OUT, bool F32A>
__device__ __forceinline__ void gemm_body(const void* __restrict__ Ap, const u16* __restrict__ W,
                                          const float* __restrict__ bias, void* __restrict__ Cout,
                                          int N, int K, float scale) {
  __shared__ __attribute__((aligned(16))) u16 As[2][128*32];
  __shared__ __attribute__((aligned(16))) u16 Bs[2][128*32];
  const u16*   A16 = (const u16*)Ap;
  const float* A32 = (const float*)Ap;
  const int t = threadIdx.x;
  const int lane = t & 63, wid = t >> 6;          // wid 0..7
  const int wr = wid >> 2, wc = wid & 3;          // 2 row-halves x 4 col-quarters
  const int g = lane >> 4, qc = lane & 15;
  const size_t m0 = (size_t)blockIdx.x * 128;
  const size_t n0 = (size_t)blockIdx.y * 128;
  f32x4 acc[4][2] = {};

  const int srow = t >> 2;                        // staging: 512 thr x 16B = 8KB tile
  const int ssch = (t & 3) ^ ((srow >> 1) & 3);   // chunk swizzle (as v1/v2/v3)

  float4 ar0, ar1;                                // F32A in-flight A registers

#define LOADA32(k0_) do {                                                  \
    const float* p = &A32[(m0 + srow)*(size_t)K + (k0_) + ssch*8];         \
    ar0 = *reinterpret_cast<const float4*>(p);                             \
    ar1 = *reinterpret_cast<const float4*>(p + 4);                         \
  } while (0)
#define WRITEA32(buf) do {                                                 \
    u32x4 pk;                                                              \
    pk.x = (u32)f2bf(ar0.x) | ((u32)f2bf(ar0.y) << 16);                    \
    pk.y = (u32)f2bf(ar0.z) | ((u32)f2bf(ar0.w) << 16);                    \
    pk.z = (u32)f2bf(ar1.x) | ((u32)f2bf(ar1.y) << 16);                    \
    pk.w = (u32)f2bf(ar1.z) | ((u32)f2bf(ar1.w) << 16);                    \
    *reinterpret_cast<u32x4*>(&As[buf][t*8]) = pk;                         \
  } while (0)
#define STAGEA16(buf, k0_) \
    async_copy16(&As[buf][t*8], &A16[(m0 + srow)*(size_t)K + (k0_) + ssch*8])
#define STAGEB(buf, k0_) \
    async_copy16(&Bs[buf][t*8], &W[(n0 + srow)*(size_t)K + (k0_) + ssch*8])

  // prologue prefetch for k0 = 0
  if (F32A) LOADA32(0); else STAGEA16(0, 0);
  STAGEB(0, 0);
  int cur = 0;
  for (int k0 = 0; k0 < K; k0 += 32) {
    if (F32A) WRITEA32(cur);    // cvt+write the regs loaded last iter (safe: As[cur]
                                // last read at iter-2, drained by iter-1's barrier)
    __syncthreads();            // drains gload_lds (vmcnt) and ds_writes (lgkm)
    if (k0 + 32 < K) {          // prefetch next tile, in flight across MFMA below
      if (F32A) LOADA32(k0 + 32); else STAGEA16(cur ^ 1, k0 + 32);
      STAGEB(cur ^ 1, k0 + 32);
    }
    bf16x8 af[4], bfr[2];
    #pragma unroll
    for (int i = 0; i < 4; ++i) {
      int r = wr*64 + i*16 + qc;
      int ch = g ^ ((r >> 1) & 3);
      af[i] = *reinterpret_cast<const bf16x8*>(&As[cur][r*32 + ch*8]);
    }
    #pragma unroll
    for (int j = 0; j < 2; ++j) {
      int r = wc*32 + j*16 + qc;
      int ch = g ^ ((r >> 1) & 3);
      bfr[j] = *reinterpret_cast<const bf16x8*>(&Bs[cur][r*32 + ch*8]);
    }
    #pragma unroll
    for (int i = 0; i < 4; ++i)
      #pragma unroll
      for (int j = 0; j < 2; ++j)
        acc[i][j] = MFMA16(af[i], bfr[j], acc[i][j]);
    cur ^= 1;
  }
#undef LOADA32
#undef WRITEA32
#undef STAGEA16
#undef STAGEB

  #pragma unroll
  for (int j = 0; j < 2; ++j) {
    size_t col = n0 + wc*32 + j*16 + qc;
    float bv = bias[col];
    #pragma unroll
    for (int i = 0; i < 4; ++i) {
      #pragma unroll
      for (int r = 0; r < 4; ++r) {
        size_t row = m0 + wr*64 + i*16 + g*4 + r;
        float v = (acc[i][j][r] + bv) * scale;
        if (BF16OUT) ((u16*)Cout)[row*N + col] = f2bf(v);
        else         ((float*)Cout)[row*N + col] = v;
      }
    }
  }
}

// Q/K/V projections fused into one launch via blockIdx.z, consuming the fp32
// input tensors DIRECTLY (conversion folded into A-staging): the separate 144MB
// tensor-cvt pass is gone. id%8 unchanged (z contributes a multiple of 512).
__global__ __launch_bounds__(512, 2)
void gemm_qkv(const float* __restrict__ query, const float* __restrict__ key,
              const float* __restrict__ value, const u16* __restrict__ wq,
              const u16* __restrict__ wk, const u16* __restrict__ wv,
              const float* __restrict__ b_q, const float* __restrict__ b_k,
              const float* __restrict__ b_v, u16* __restrict__ Qp,
              u16* __restrict__ Kp, u16* __restrict__ Vp, float scaleQ) {
  const float* A; const u16* W; const float* bias; u16* C; float scale;
  switch (blockIdx.z) {
    case 0:  A = query; W = wq; bias = b_q; C = Qp; scale = scaleQ; break;
    case 1:  A = key;   W = wk; bias = b_k; C = Kp; scale = 1.0f;   break;
    default: A = value; W = wv; bias = b_v; C = Vp; scale = 1.0f;   break;
  }
  gemm_body<true, true>(A, W, bias, C, 1024, 1024, scale);
}

__global__ __launch_bounds__(512, 2)
void gemm_out(const u16* __restrict__ A, const u16* __restrict__ W,
              const float* __restrict__ bias, float* __restrict__ C) {
  gemm_body<false, false>(A, W, bias, C, 1024, 1024, 1.0f);
}

// --------------------------------------------------------------- flash attention v17
// FROZEN at v17 (validated PASS, 113.5 us). Session evidence: max/defer machinery
// is load-bearing (v18: removal -> 4.9e-2); asm permlane32_swap is hazard-unsafe
// (v16: NaN); accL denominator-on-MFMA spills registers at launch_bounds(512,4)
// (v19: +330 MB scratch traffic, 200 us). Do not touch without new evidence.
__global__ __launch_bounds__(512, 4)
void flash_attn3(const u16* __restrict__ Qp, const u16* __restrict__ Kp,
                 const u16* __restrict__ Vp, u16* __restrict__ O) {
  __shared__ __attribute__((aligned(16))) u16 Ks[2][64*64];
  __shared__ __attribute__((aligned(16))) u16 Vt[3][64*64];
  const int t = threadIdx.x;
  const int w = t >> 6, lane = t & 63;
  const int l31 = lane & 31, hi = lane >> 5;
  const int bh = blockIdx.x;                    // bh fastest -> id%8 = bh%8 (XCD)
  const size_t rowbase = (size_t)(bh >> 4) * 2048;
  const int hoff = (bh & 15) * 64;
  const int q0 = blockIdx.y * 256 + w * 32;
  const float THR = 11.5415603f;   // 8 * log2(e)

  // Q B-frags (Q pre-scaled by 0.125*log2(e) in projection epilogue)
  bf16x8 bq[4];
  {
    const u16* qp = &Qp[(rowbase + q0 + l31) * 1024 + hoff + hi * 8];
    #pragma unroll
    for (int dd = 0; dd < 4; ++dd) bq[dd] = *reinterpret_cast<const bf16x8*>(qp + dd*16);
  }

  f32x16 accO[2] = {};
  float m_run = 0.f, l_run = 0.f;   // log2 domain; scores tracked relative to m_run
  u32 pwp[2][8];                    // packed P(t-1)

  const int kvr_s = t >> 3, c_s = t & 7;
  const int sc_s = c_s ^ ((kvr_s >> 3) & 7);      // pre-swizzled K source chunk
  const int vd0_s = (t & 7) * 8;
  const int vcs = kvr_s >> 3;

  // prologue: tile 0
  async_copy16(&Ks[0][t*8], &Kp[(rowbase + kvr_s)*1024 + hoff + sc_s*8]);
  bf16x8 vreg = *reinterpret_cast<const bf16x8*>(&Vp[(rowbase + kvr_s)*1024 + hoff + vd0_s]);

  int wi = 0, ri = 2;   // V write = kv%3, V read (tile kv-1) = (kv+2)%3
  for (int kv = 0; kv < 32; ++kv) {
    const int kb = kv & 1;
    u16* vw = &Vt[0][0] + wi*4096;
    const u16* vrd = &Vt[0][0] + ri*4096;

    // V(kv) regs -> LDS, transposed + chunk-swizzled
    #pragma unroll
    for (int j = 0; j < 8; ++j) {
      int d = vd0_s + j;
      vw[d*64 + ((vcs ^ ((d>>3)&7))*8) + (kvr_s & 7)] = (u16)vreg[j];
    }
    __syncthreads();
    if (kv < 31) {
      const size_t nb = rowbase + (size_t)(kv+1)*64;
      async_copy16(&Ks[kb^1][t*8], &Kp[(nb + kvr_s)*1024 + hoff + sc_s*8]);
      vreg = *reinterpret_cast<const bf16x8*>(&Vp[(nb + kvr_s)*1024 + hoff + vd0_s]);
    }

    // ---- QK^T(kv), swapped; C initialized to -m_run so sacc = S - m_old
    f32x16 sacc[2];
    {
      const float negm = -m_run;
      #pragma unroll
      for (int i = 0; i < 16; ++i) { sacc[0][i] = negm; sacc[1][i] = negm; }
    }
    #pragma unroll
    for (int n = 0; n < 2; ++n) {
      int kvr = n*32 + l31;
      int swz = (kvr >> 3) & 7;
      #pragma unroll
      for (int dd = 0; dd < 4; ++dd) {
        int ch = (2*dd + hi) ^ swz;
        bf16x8 ak = *reinterpret_cast<const bf16x8*>(&Ks[kb][kvr*64 + ch*8]);
        sacc[n] = MFMA32(ak, bq[dd], sacc[n]);
      }
    }

    // ---- deferred PV(kv-1): overlaps softmax VALU below (independent regs)
    if (kv > 0) {
      #pragma unroll
      for (int ks = 0; ks < 4; ++ks) {
        const int n = ks >> 1, kp = ks & 1;
        u32 wA0 = pwp[n][4*kp+0], wA1 = pwp[n][4*kp+1];
        u32 wB0 = pwp[n][4*kp+2], wB1 = pwp[n][4*kp+3];
        u32 s0 = hi ? wA0 : wB0, s1 = hi ? wA1 : wB1;
        u32 r0 = (u32)__shfl_xor((int)s0, 32);
        u32 r1 = (u32)__shfl_xor((int)s1, 32);
        u32 k0 = hi ? wB0 : wA0, k1 = hi ? wB1 : wA1;
        u32x4 fu;
        fu.x = hi ? r0 : k0; fu.y = hi ? r1 : k1;
        fu.z = hi ? k0 : r0; fu.w = hi ? k1 : r1;
        bf16x8 pa = __builtin_bit_cast(bf16x8, fu);
        #pragma unroll
        for (int dt = 0; dt < 2; ++dt) {
          int d = dt*32 + l31;
          int ch = (2*ks + hi) ^ ((d>>3)&7);
          bf16x8 bv = *reinterpret_cast<const bf16x8*>(&vrd[d*64 + ch*8]);
          accO[dt] = MFMA32(pa, bv, accO[dt]);
        }
      }
    }

    // ---- softmax(kv): 3-ary max nest (v_max3-fusable)
    float a0 = fmaxf(fmaxf(sacc[0][0],sacc[0][1]),sacc[0][2]);
    float a1 = fmaxf(fmaxf(sacc[0][3],sacc[0][4]),sacc[0][5]);
    float a2 = fmaxf(fmaxf(sacc[0][6],sacc[0][7]),sacc[0][8]);
    float a3 = fmaxf(fmaxf(sacc[0][9],sacc[0][10]),sacc[0][11]);
    float a4 = fmaxf(fmaxf(sacc[0][12],sacc[0][13]),sacc[0][14]);
    float a5 = fmaxf(fmaxf(sacc[0][15],sacc[1][0]),sacc[1][1]);
    float a6 = fmaxf(fmaxf(sacc[1][2],sacc[1][3]),sacc[1][4]);
    float a7 = fmaxf(fmaxf(sacc[1][5],sacc[1][6]),sacc[1][7]);
    float a8 = fmaxf(fmaxf(sacc[1][8],sacc[1][9]),sacc[1][10]);
    float a9 = fmaxf(fmaxf(sacc[1][11],sacc[1][12]),sacc[1][13]);
    float aA = fmaxf(sacc[1][14],sacc[1][15]);
    float b0 = fmaxf(fmaxf(a0,a1),a2);
    float b1 = fmaxf(fmaxf(a3,a4),a5);
    float b2 = fmaxf(fmaxf(a6,a7),a8);
    float b3 = fmaxf(a9,aA);
    float mloc = fmaxf(fmaxf(b0,b1),fmaxf(b2,b3));
    float mx = fmaxf(mloc, __shfl_xor(mloc, 32));   // relative to m_run

    if (__any(mx > THR)) {   // rare: max grew beyond the defer threshold
      float dm = fmaxf(mx, 0.f);
      float alpha = fast_exp2(-dm);
      m_run += dm;
      l_run *= alpha;
      #pragma unroll
      for (int n = 0; n < 2; ++n)
        #pragma unroll
        for (int r = 0; r < 16; ++r) sacc[n][r] -= dm;
      #pragma unroll
      for (int r = 0; r < 16; ++r) {
        int qrow = (r&3) + 8*(r>>2) + 4*hi;
        float ar = __shfl(alpha, qrow);
        accO[0][r] *= ar; accO[1][r] *= ar;
      }
    }

    // ---- exp2 in place (raw v_exp_f32), RNE f2bf pack, sum tree
    #pragma unroll
    for (int n = 0; n < 2; ++n)
      #pragma unroll
      for (int r = 0; r < 16; ++r) sacc[n][r] = fast_exp2(sacc[n][r]);
    #pragma unroll
    for (int n = 0; n < 2; ++n)
      #pragma unroll
      for (int i = 0; i < 8; ++i)
        pwp[n][i] = (u32)f2bf(sacc[n][2*i]) | ((u32)f2bf(sacc[n][2*i+1]) << 16);
    float ts[16];
    #pragma unroll
    for (int i = 0; i < 16; ++i) ts[i] = sacc[0][i] + sacc[1][i];
    #pragma unroll
    for (int off = 8; off >= 1; off >>= 1)
      #pragma unroll
      for (int i = 0; i < off; ++i) ts[i] += ts[i + off];
    l_run += ts[0] + __shfl_xor(ts[0], 32);

    wi = (wi == 2) ? 0 : wi + 1;
    ri = (ri == 2) ? 0 : ri + 1;
  }

  // ---- epilogue PV(31)
  {
    const u16* vrd = &Vt[0][0] + ri*4096;
    #pragma unroll
    for (int ks = 0; ks < 4; ++ks) {
      const int n = ks >> 1, kp = ks & 1;
      u32 wA0 = pwp[n][4*kp+0], wA1 = pwp[n][4*kp+1];
      u32 wB0 = pwp[n][4*kp+2], wB1 = pwp[n][4*kp+3];
      u32 s0 = hi ? wA0 : wB0, s1 = hi ? wA1 : wB1;
      u32 r0 = (u32)__shfl_xor((int)s0, 32);
      u32 r1 = (u32)__shfl_xor((int)s1, 32);
      u32 k0 = hi ? wB0 : wA0, k1 = hi ? wB1 : wA1;
      u32x4 fu;
      fu.x = hi ? r0 : k0; fu.y = hi ? r1 : k1;
      fu.z = hi ? k0 : r0; fu.w = hi ? k1 : r1;
      bf16x8 pa = __builtin_bit_cast(bf16x8, fu);
      #pragma unroll
      for (int dt = 0; dt < 2; ++dt) {
        int d = dt*32 + l31;
        int ch = (2*ks + hi) ^ ((d>>3)&7);
        bf16x8 bv = *reinterpret_cast<const bf16x8*>(&vrd[d*64 + ch*8]);
        accO[dt] = MFMA32(pa, bv, accO[dt]);
      }
    }
  }

  // ---- epilogue: O[q'][d] * (1/l[q']), l for row q' pulled from lane q'
  float linv = 1.0f / l_run;
  #pragma unroll
  for (int r = 0; r < 16; ++r) {
    int qrow = (r&3) + 8*(r>>2) + 4*hi;
    float lv = __shfl(linv, qrow);
    size_t orow = rowbase + q0 + qrow;
    O[orow*1024 + hoff + l31]      = f2bf(accO[0][r] * lv);
    O[orow*1024 + hoff + 32 + l31] = f2bf(accO[1][r] * lv);
  }
}

// ------------------------------------------------------------------------------
extern "C" void kernel_launch(void* const* d_in, const int* in_sizes, int n_in,
                              void* d_out, int out_size, void* d_ws, size_t ws_size,
                              hipStream_t stream) {
  (void)in_sizes; (void)n_in; (void)out_size; (void)ws_size;
  const float* query = (const float*)d_in[0];
  const float* key   = (const float*)d_in[1];
  const float* value = (const float*)d_in[2];
  const float* W_q   = (const float*)d_in[3];
  const float* b_q   = (const float*)d_in[4];
  const float* W_k   = (const float*)d_in[5];
  const float* b_k   = (const float*)d_in[6];
  const float* W_v   = (const float*)d_in[7];
  const float* b_v   = (const float*)d_in[8];
  const float* W_o   = (const float*)d_in[9];
  const float* b_o   = (const float*)d_in[10];

  const size_t sz_t = (size_t)8192 * 1024;
  const size_t sz_w = (size_t)1024 * 1024;
  u16* ws = (u16*)d_ws;
  u16* xq = ws;                 // attn-output staging (bf16)
  u16* Qp = ws + 3*sz_t;
  u16* Kp = ws + 4*sz_t;
  u16* Vp = ws + 5*sz_t;
  u16* wq = ws + 6*sz_t;
  u16* wk = wq + sz_w;
  u16* wv = wq + 2*sz_w;
  u16* wo = wq + 3*sz_w;

  const float SCL = 0.125f * 1.44269504089f;  // softmax scale, folded into Q proj

  // weights only: fp32 -> bf16 (4MB total; the 144MB tensor cvt is now folded
  // into gemm_qkv's A-staging)
  cvt4_kernel<<<dim3(512, 4), 256, 0, stream>>>(W_q, W_k, W_v, W_o,
                                                wq, wk, wv, wo, (int)(sz_w/4));

  // fused QKV projection from fp32 inputs: grid (m-tiles, n-tiles, 3)
  gemm_qkv<<<dim3(8192/128, 1024/128, 3), 512, 0, stream>>>(
      query, key, value, wq, wk, wv, b_q, b_k, b_v, Qp, Kp, Vp, SCL);

  // grid = (bh, q-tiles): K/V-panel sharers co-locate per XCD
  flash_attn3<<<dim3(64, 8), 512, 0, stream>>>(Qp, Kp, Vp, xq);

  gemm_out<<<dim3(8192/128, 1024/128), 512, 0, stream>>>(xq, wo, b_o, (float*)d_out);
}

// Round 11
// 211.239 us; speedup vs baseline: 1.5580x; 1.0582x over previous
//
#include <hip/hip_runtime.h>
#include <hip/hip_bf16.h>
#include <cstdint>
#include <cstddef>

typedef unsigned short u16;
typedef unsigned int u32;
typedef __attribute__((ext_vector_type(8))) short bf16x8;   // 8 bf16 = 4 VGPR
typedef __attribute__((ext_vector_type(4))) float f32x4;    // 16x16 MFMA C/D
typedef __attribute__((ext_vector_type(16))) float f32x16;  // 32x32 MFMA C/D
typedef __attribute__((ext_vector_type(2))) unsigned int u32x2;
typedef __attribute__((ext_vector_type(4))) unsigned int u32x4;
typedef __attribute__((ext_vector_type(4))) unsigned short u16x4;

#define MFMA16(A,B,C) __builtin_amdgcn_mfma_f32_16x16x32_bf16(A,B,C,0,0,0)
#define MFMA32(A,B,C) __builtin_amdgcn_mfma_f32_32x32x16_bf16(A,B,C,0,0,0)

// Compiler-visible permlane32_swap (T12 recipe): unlike the raw inline-asm form
// (v16: NaN — post-RA hazard recognizer can't see inside asm strings), the
// builtin is scheduled + hazard-managed by the compiler. Semantics:
//   r = swap(a,b):  r.x = (a.lanes[0:31], b.lanes[0:31])   [= old a.lo | b.lo]
//                   r.y = (a.lanes[32:63], b.lanes[32:63]) [= old a.hi | b.hi]
#if defined(__has_builtin)
#if __has_builtin(__builtin_amdgcn_permlane32_swap)
#define HAVE_PERMSWAP 1
#endif
#endif

__device__ __forceinline__ u16 f2bf(float x) {
  __hip_bfloat16 h = __float2bfloat16(x);
  return __builtin_bit_cast(u16, h);
}

// raw v_exp_f32: single trans-pipe instruction (libm exp2f w/o fast-math takes
// the guarded __ocml path). Inputs here are <= ~11.6 (max-tracked); deep
// negatives flush to 0, which is exactly the softmax tail behavior we want.
__device__ __forceinline__ float fast_exp2(float x) {
  float r;
  asm("v_exp_f32 %0, %1" : "=v"(r) : "v"(x));
  return r;
}

// cross-half exchange: value of x from lane^32, bit-identical to __shfl_xor(x,32)
__device__ __forceinline__ float xhalf(float x, int hi) {
#if HAVE_PERMSWAP
  u32 m = __builtin_bit_cast(u32, x);
  u32x2 r = __builtin_amdgcn_permlane32_swap(m, m, false, false);
  return __builtin_bit_cast(float, hi ? r.x : r.y);
#else
  (void)hi;
  return __shfl_xor(x, 32);
#endif
}

__device__ __forceinline__ void async_copy16(u16* lds, const u16* g) {
  __builtin_amdgcn_global_load_lds(
      (const __attribute__((address_space(1))) void*)g,
      (__attribute__((address_space(3))) void*)lds, 16, 0, 0);
}

// ------------------------------------------- fp32 -> bf16, up to 4 arrays/launch
__global__ void cvt4_kernel(const float* __restrict__ i0, const float* __restrict__ i1,
                            const float* __restrict__ i2, const float* __restrict__ i3,
                            u16* __restrict__ o0, u16* __restrict__ o1,
                            u16* __restrict__ o2, u16* __restrict__ o3, int n4) {
  const float* in; u16* out;
  switch (blockIdx.y) {
    case 0:  in = i0; out = o0; break;
    case 1:  in = i1; out = o1; break;
    case 2:  in = i2; out = o2; break;
    default: in = i3; out = o3; break;
  }
  int i = blockIdx.x * blockDim.x + threadIdx.x;
  int stride = gridDim.x * blockDim.x;
  for (; i < n4; i += stride) {
    float4 v = reinterpret_cast<const float4*>(in)[i];
    u16x4 o;
    o.x = f2bf(v.x); o.y = f2bf(v.y); o.z = f2bf(v.z); o.w = f2bf(v.w);
    reinterpret_cast<u16x4*>(out)[i] = o;
  }
}

// ------------------------------------------------- GEMM NT: C = (A*W^T + bias)*scale
// v4 (validated R10): 512-thread 8-wave 2x4, dbuf, F32A in-staging conversion.
// Grid (m-tiles, n-tiles[, qkv]): A-panel sharers co-locate per XCD (id%8 = x%8).
template<bool BF16OUT, bool F32A>
__device__ __forceinline__ void gemm_body(const void* __restrict__ Ap, const u16* __restrict__ W,
                                          const float* __restrict__ bias, void* __restrict__ Cout,
                                          int N, int K, float scale) {
  __shared__ __attribute__((aligned(16))) u16 As[2][128*32];
  __shared__ __attribute__((aligned(16))) u16 Bs[2][128*32];
  const u16*   A16 = (const u16*)Ap;
  const float* A32 = (const float*)Ap;
  const int t = threadIdx.x;
  const int lane = t & 63, wid = t >> 6;          // wid 0..7
  const int wr = wid >> 2, wc = wid & 3;          // 2 row-halves x 4 col-quarters
  const int g = lane >> 4, qc = lane & 15;
  const size_t m0 = (size_t)blockIdx.x * 128;
  const size_t n0 = (size_t)blockIdx.y * 128;
  f32x4 acc[4][2] = {};

  const int srow = t >> 2;                        // staging: 512 thr x 16B = 8KB tile
  const int ssch = (t & 3) ^ ((srow >> 1) & 3);   // chunk swizzle (as v1/v2/v3)

  float4 ar0, ar1;                                // F32A in-flight A registers

#define LOADA32(k0_) do {                                                  \
    const float* p = &A32[(m0 + srow)*(size_t)K + (k0_) + ssch*8];         \
    ar0 = *reinterpret_cast<const float4*>(p);                             \
    ar1 = *reinterpret_cast<const float4*>(p + 4);                         \
  } while (0)
#define WRITEA32(buf) do {                                                 \
    u32x4 pk;                                                              \
    pk.x = (u32)f2bf(ar0.x) | ((u32)f2bf(ar0.y) << 16);                    \
    pk.y = (u32)f2bf(ar0.z) | ((u32)f2bf(ar0.w) << 16);                    \
    pk.z = (u32)f2bf(ar1.x) | ((u32)f2bf(ar1.y) << 16);                    \
    pk.w = (u32)f2bf(ar1.z) | ((u32)f2bf(ar1.w) << 16);                    \
    *reinterpret_cast<u32x4*>(&As[buf][t*8]) = pk;                         \
  } while (0)
#define STAGEA16(buf, k0_) \
    async_copy16(&As[buf][t*8], &A16[(m0 + srow)*(size_t)K + (k0_) + ssch*8])
#define STAGEB(buf, k0_) \
    async_copy16(&Bs[buf][t*8], &W[(n0 + srow)*(size_t)K + (k0_) + ssch*8])

  // prologue prefetch for k0 = 0
  if (F32A) LOADA32(0); else STAGEA16(0, 0);
  STAGEB(0, 0);
  int cur = 0;
  for (int k0 = 0; k0 < K; k0 += 32) {
    if (F32A) WRITEA32(cur);    // cvt+write the regs loaded last iter (safe: As[cur]
                                // last read at iter-2, drained by iter-1's barrier)
    __syncthreads();            // drains gload_lds (vmcnt) and ds_writes (lgkm)
    if (k0 + 32 < K) {          // prefetch next tile, in flight across MFMA below
      if (F32A) LOADA32(k0 + 32); else STAGEA16(cur ^ 1, k0 + 32);
      STAGEB(cur ^ 1, k0 + 32);
    }
    bf16x8 af[4], bfr[2];
    #pragma unroll
    for (int i = 0; i < 4; ++i) {
      int r = wr*64 + i*16 + qc;
      int ch = g ^ ((r >> 1) & 3);
      af[i] = *reinterpret_cast<const bf16x8*>(&As[cur][r*32 + ch*8]);
    }
    #pragma unroll
    for (int j = 0; j < 2; ++j) {
      int r = wc*32 + j*16 + qc;
      int ch = g ^ ((r >> 1) & 3);
      bfr[j] = *reinterpret_cast<const bf16x8*>(&Bs[cur][r*32 + ch*8]);
    }
    #pragma unroll
    for (int i = 0; i < 4; ++i)
      #pragma unroll
      for (int j = 0; j < 2; ++j)
        acc[i][j] = MFMA16(af[i], bfr[j], acc[i][j]);
    cur ^= 1;
  }
#undef LOADA32
#undef WRITEA32
#undef STAGEA16
#undef STAGEB

  #pragma unroll
  for (int j = 0; j < 2; ++j) {
    size_t col = n0 + wc*32 + j*16 + qc;
    float bv = bias[col];
    #pragma unroll
    for (int i = 0; i < 4; ++i) {
      #pragma unroll
      for (int r = 0; r < 4; ++r) {
        size_t row = m0 + wr*64 + i*16 + g*4 + r;
        float v = (acc[i][j][r] + bv) * scale;
        if (BF16OUT) ((u16*)Cout)[row*N + col] = f2bf(v);
        else         ((float*)Cout)[row*N + col] = v;
      }
    }
  }
}

// Q/K/V projections fused into one launch via blockIdx.z, consuming the fp32
// input tensors DIRECTLY (conversion folded into A-staging).
__global__ __launch_bounds__(512, 2)
void gemm_qkv(const float* __restrict__ query, const float* __restrict__ key,
              const float* __restrict__ value, const u16* __restrict__ wq,
              const u16* __restrict__ wk, const u16* __restrict__ wv,
              const float* __restrict__ b_q, const float* __restrict__ b_k,
              const float* __restrict__ b_v, u16* __restrict__ Qp,
              u16* __restrict__ Kp, u16* __restrict__ Vp, float scaleQ) {
  const float* A; const u16* W; const float* bias; u16* C; float scale;
  switch (blockIdx.z) {
    case 0:  A = query; W = wq; bias = b_q; C = Qp; scale = scaleQ; break;
    case 1:  A = key;   W = wk; bias = b_k; C = Kp; scale = 1.0f;   break;
    default: A = value; W = wv; bias = b_v; C = Vp; scale = 1.0f;   break;
  }
  gemm_body<true, true>(A, W, bias, C, 1024, 1024, scale);
}

__global__ __launch_bounds__(512, 2)
void gemm_out(const u16* __restrict__ A, const u16* __restrict__ W,
              const float* __restrict__ bias, float* __restrict__ C) {
  gemm_body<false, false>(A, W, bias, C, 1024, 1024, 1.0f);
}

// --------------------------------------------------------------- flash attention v20
// = v17 with ONE principled change: the half-exchange network (PV recombination
// x2/ks, mx reduce, ts reduce) now uses __builtin_amdgcn_permlane32_swap when
// available — the COMPILER-VISIBLE form (hazards handled), not v16's unsafe raw
// asm. Values are bit-identical to the shfl_xor network (mapping re-derived:
// r.x=(A.lo,B.lo)=fu.x, r.y=(A.hi,B.hi)=fu.z). Falls back to the validated v17
// network if the builtin is absent. Max/defer machinery untouched (load-bearing,
// v18). accL denominator stays out (v19: register spill).
__global__ __launch_bounds__(512, 4)
void flash_attn3(const u16* __restrict__ Qp, const u16* __restrict__ Kp,
                 const u16* __restrict__ Vp, u16* __restrict__ O) {
  __shared__ __attribute__((aligned(16))) u16 Ks[2][64*64];
  __shared__ __attribute__((aligned(16))) u16 Vt[3][64*64];
  const int t = threadIdx.x;
  const int w = t >> 6, lane = t & 63;
  const int l31 = lane & 31, hi = lane >> 5;
  const int bh = blockIdx.x;                    // bh fastest -> id%8 = bh%8 (XCD)
  const size_t rowbase = (size_t)(bh >> 4) * 2048;
  const int hoff = (bh & 15) * 64;
  const int q0 = blockIdx.y * 256 + w * 32;
  const float THR = 11.5415603f;   // 8 * log2(e)

  // Q B-frags (Q pre-scaled by 0.125*log2(e) in projection epilogue)
  bf16x8 bq[4];
  {
    const u16* qp = &Qp[(rowbase + q0 + l31) * 1024 + hoff + hi * 8];
    #pragma unroll
    for (int dd = 0; dd < 4; ++dd) bq[dd] = *reinterpret_cast<const bf16x8*>(qp + dd*16);
  }

  f32x16 accO[2] = {};
  float m_run = 0.f, l_run = 0.f;   // log2 domain; scores tracked relative to m_run
  u32 pwp[2][8];                    // packed P(t-1)

  const int kvr_s = t >> 3, c_s = t & 7;
  const int sc_s = c_s ^ ((kvr_s >> 3) & 7);      // pre-swizzled K source chunk
  const int vd0_s = (t & 7) * 8;
  const int vcs = kvr_s >> 3;

  // prologue: tile 0
  async_copy16(&Ks[0][t*8], &Kp[(rowbase + kvr_s)*1024 + hoff + sc_s*8]);
  bf16x8 vreg = *reinterpret_cast<const bf16x8*>(&Vp[(rowbase + kvr_s)*1024 + hoff + vd0_s]);

  // PV A-fragment recombination: fu.x=(A0.lo,B0.lo) fu.y=(A1.lo,B1.lo)
  //                              fu.z=(A0.hi,B0.hi) fu.w=(A1.hi,B1.hi)
#if HAVE_PERMSWAP
#define PV_FRAG(fu, wA0_, wA1_, wB0_, wB1_) do {                              \
    u32x2 r0_ = __builtin_amdgcn_permlane32_swap((wA0_), (wB0_), false, false);\
    u32x2 r1_ = __builtin_amdgcn_permlane32_swap((wA1_), (wB1_), false, false);\
    fu.x = r0_.x; fu.y = r1_.x; fu.z = r0_.y; fu.w = r1_.y;                   \
  } while (0)
#else
#define PV_FRAG(fu, wA0_, wA1_, wB0_, wB1_) do {                              \
    u32 s0 = hi ? (wA0_) : (wB0_), s1 = hi ? (wA1_) : (wB1_);                 \
    u32 r0 = (u32)__shfl_xor((int)s0, 32);                                    \
    u32 r1 = (u32)__shfl_xor((int)s1, 32);                                    \
    u32 k0 = hi ? (wB0_) : (wA0_), k1 = hi ? (wB1_) : (wA1_);                 \
    fu.x = hi ? r0 : k0; fu.y = hi ? r1 : k1;                                 \
    fu.z = hi ? k0 : r0; fu.w = hi ? k1 : r1;                                 \
  } while (0)
#endif

  int wi = 0, ri = 2;   // V write = kv%3, V read (tile kv-1) = (kv+2)%3
  for (int kv = 0; kv < 32; ++kv) {
    const int kb = kv & 1;
    u16* vw = &Vt[0][0] + wi*4096;
    const u16* vrd = &Vt[0][0] + ri*4096;

    // V(kv) regs -> LDS, transposed + chunk-swizzled
    #pragma unroll
    for (int j = 0; j < 8; ++j) {
      int d = vd0_s + j;
      vw[d*64 + ((vcs ^ ((d>>3)&7))*8) + (kvr_s & 7)] = (u16)vreg[j];
    }
    __syncthreads();
    if (kv < 31) {
      const size_t nb = rowbase + (size_t)(kv+1)*64;
      async_copy16(&Ks[kb^1][t*8], &Kp[(nb + kvr_s)*1024 + hoff + sc_s*8]);
      vreg = *reinterpret_cast<const bf16x8*>(&Vp[(nb + kvr_s)*1024 + hoff + vd0_s]);
    }

    // ---- QK^T(kv), swapped; C initialized to -m_run so sacc = S - m_old
    f32x16 sacc[2];
    {
      const float negm = -m_run;
      #pragma unroll
      for (int i = 0; i < 16; ++i) { sacc[0][i] = negm; sacc[1][i] = negm; }
    }
    #pragma unroll
    for (int n = 0; n < 2; ++n) {
      int kvr = n*32 + l31;
      int swz = (kvr >> 3) & 7;
      #pragma unroll
      for (int dd = 0; dd < 4; ++dd) {
        int ch = (2*dd + hi) ^ swz;
        bf16x8 ak = *reinterpret_cast<const bf16x8*>(&Ks[kb][kvr*64 + ch*8]);
        sacc[n] = MFMA32(ak, bq[dd], sacc[n]);
      }
    }

    // ---- deferred PV(kv-1): overlaps softmax VALU below (independent regs)
    if (kv > 0) {
      #pragma unroll
      for (int ks = 0; ks < 4; ++ks) {
        const int n = ks >> 1, kp = ks & 1;
        u32x4 fu;
        PV_FRAG(fu, pwp[n][4*kp+0], pwp[n][4*kp+1], pwp[n][4*kp+2], pwp[n][4*kp+3]);
        bf16x8 pa = __builtin_bit_cast(bf16x8, fu);
        #pragma unroll
        for (int dt = 0; dt < 2; ++dt) {
          int d = dt*32 + l31;
          int ch = (2*ks + hi) ^ ((d>>3)&7);
          bf16x8 bv = *reinterpret_cast<const bf16x8*>(&vrd[d*64 + ch*8]);
          accO[dt] = MFMA32(pa, bv, accO[dt]);
        }
      }
    }

    // ---- softmax(kv): 3-ary max nest (v_max3-fusable)
    float a0 = fmaxf(fmaxf(sacc[0][0],sacc[0][1]),sacc[0][2]);
    float a1 = fmaxf(fmaxf(sacc[0][3],sacc[0][4]),sacc[0][5]);
    float a2 = fmaxf(fmaxf(sacc[0][6],sacc[0][7]),sacc[0][8]);
    float a3 = fmaxf(fmaxf(sacc[0][9],sacc[0][10]),sacc[0][11]);
    float a4 = fmaxf(fmaxf(sacc[0][12],sacc[0][13]),sacc[0][14]);
    float a5 = fmaxf(fmaxf(sacc[0][15],sacc[1][0]),sacc[1][1]);
    float a6 = fmaxf(fmaxf(sacc[1][2],sacc[1][3]),sacc[1][4]);
    float a7 = fmaxf(fmaxf(sacc[1][5],sacc[1][6]),sacc[1][7]);
    float a8 = fmaxf(fmaxf(sacc[1][8],sacc[1][9]),sacc[1][10]);
    float a9 = fmaxf(fmaxf(sacc[1][11],sacc[1][12]),sacc[1][13]);
    float aA = fmaxf(sacc[1][14],sacc[1][15]);
    float b0 = fmaxf(fmaxf(a0,a1),a2);
    float b1 = fmaxf(fmaxf(a3,a4),a5);
    float b2 = fmaxf(fmaxf(a6,a7),a8);
    float b3 = fmaxf(a9,aA);
    float mloc = fmaxf(fmaxf(b0,b1),fmaxf(b2,b3));
    float mx = fmaxf(mloc, xhalf(mloc, hi));   // relative to m_run

    if (__any(mx > THR)) {   // rare: max grew beyond the defer threshold
      float dm = fmaxf(mx, 0.f);
      float alpha = fast_exp2(-dm);
      m_run += dm;
      l_run *= alpha;
      #pragma unroll
      for (int n = 0; n < 2; ++n)
        #pragma unroll
        for (int r = 0; r < 16; ++r) sacc[n][r] -= dm;
      #pragma unroll
      for (int r = 0; r < 16; ++r) {
        int qrow = (r&3) + 8*(r>>2) + 4*hi;
        float ar = __shfl(alpha, qrow);
        accO[0][r] *= ar; accO[1][r] *= ar;
      }
    }

    // ---- exp2 in place (raw v_exp_f32), RNE f2bf pack, sum tree
    #pragma unroll
    for (int n = 0; n < 2; ++n)
      #pragma unroll
      for (int r = 0; r < 16; ++r) sacc[n][r] = fast_exp2(sacc[n][r]);
    #pragma unroll
    for (int n = 0; n < 2; ++n)
      #pragma unroll
      for (int i = 0; i < 8; ++i)
        pwp[n][i] = (u32)f2bf(sacc[n][2*i]) | ((u32)f2bf(sacc[n][2*i+1]) << 16);
    float ts[16];
    #pragma unroll
    for (int i = 0; i < 16; ++i) ts[i] = sacc[0][i] + sacc[1][i];
    #pragma unroll
    for (int off = 8; off >= 1; off >>= 1)
      #pragma unroll
      for (int i = 0; i < off; ++i) ts[i] += ts[i + off];
    l_run += ts[0] + xhalf(ts[0], hi);

    wi = (wi == 2) ? 0 : wi + 1;
    ri = (ri == 2) ? 0 : ri + 1;
  }

  // ---- epilogue PV(31)
  {
    const u16* vrd = &Vt[0][0] + ri*4096;
    #pragma unroll
    for (int ks = 0; ks < 4; ++ks) {
      const int n = ks >> 1, kp = ks & 1;
      u32x4 fu;
      PV_FRAG(fu, pwp[n][4*kp+0], pwp[n][4*kp+1], pwp[n][4*kp+2], pwp[n][4*kp+3]);
      bf16x8 pa = __builtin_bit_cast(bf16x8, fu);
      #pragma unroll
      for (int dt = 0; dt < 2; ++dt) {
        int d = dt*32 + l31;
        int ch = (2*ks + hi) ^ ((d>>3)&7);
        bf16x8 bv = *reinterpret_cast<const bf16x8*>(&vrd[d*64 + ch*8]);
        accO[dt] = MFMA32(pa, bv, accO[dt]);
      }
    }
  }
#undef PV_FRAG

  // ---- epilogue: O[q'][d] * (1/l[q']), l for row q' pulled from lane q'
  float linv = 1.0f / l_run;
  #pragma unroll
  for (int r = 0; r < 16; ++r) {
    int qrow = (r&3) + 8*(r>>2) + 4*hi;
    float lv = __shfl(linv, qrow);
    size_t orow = rowbase + q0 + qrow;
    O[orow*1024 + hoff + l31]      = f2bf(accO[0][r] * lv);
    O[orow*1024 + hoff + 32 + l31] = f2bf(accO[1][r] * lv);
  }
}

// ------------------------------------------------------------------------------
extern "C" void kernel_launch(void* const* d_in, const int* in_sizes, int n_in,
                              void* d_out, int out_size, void* d_ws, size_t ws_size,
                              hipStream_t stream) {
  (void)in_sizes; (void)n_in; (void)out_size; (void)ws_size;
  const float* query = (const float*)d_in[0];
  const float* key   = (const float*)d_in[1];
  const float* value = (const float*)d_in[2];
  const float* W_q   = (const float*)d_in[3];
  const float* b_q   = (const float*)d_in[4];
  const float* W_k   = (const float*)d_in[5];
  const float* b_k   = (const float*)d_in[6];
  const float* W_v   = (const float*)d_in[7];
  const float* b_v   = (const float*)d_in[8];
  const float* W_o   = (const float*)d_in[9];
  const float* b_o   = (const float*)d_in[10];

  const size_t sz_t = (size_t)8192 * 1024;
  const size_t sz_w = (size_t)1024 * 1024;
  u16* ws = (u16*)d_ws;
  u16* xq = ws;                 // attn-output staging (bf16)
  u16* Qp = ws + 3*sz_t;
  u16* Kp = ws + 4*sz_t;
  u16* Vp = ws + 5*sz_t;
  u16* wq = ws + 6*sz_t;
  u16* wk = wq + sz_w;
  u16* wv = wq + 2*sz_w;
  u16* wo = wq + 3*sz_w;

  const float SCL = 0.125f * 1.44269504089f;  // softmax scale, folded into Q proj

  // weights only: fp32 -> bf16 (4MB total; the 144MB tensor cvt is folded
  // into gemm_qkv's A-staging)
  cvt4_kernel<<<dim3(512, 4), 256, 0, stream>>>(W_q, W_k, W_v, W_o,
                                                wq, wk, wv, wo, (int)(sz_w/4));

  // fused QKV projection from fp32 inputs: grid (m-tiles, n-tiles, 3)
  gemm_qkv<<<dim3(8192/128, 1024/128, 3), 512, 0, stream>>>(
      query, key, value, wq, wk, wv, b_q, b_k, b_v, Qp, Kp, Vp, SCL);

  // grid = (bh, q-tiles): K/V-panel sharers co-locate per XCD
  flash_attn3<<<dim3(64, 8), 512, 0, stream>>>(Qp, Kp, Vp, xq);

  gemm_out<<<dim3(8192/128, 1024/128), 512, 0, stream>>>(xq, wo, b_o, (float*)d_out);
}